// Round 1
// baseline (2969.867 us; speedup 1.0000x reference)
//
#include <hip/hip_runtime.h>

#define NM 1200
#define PP 719400      // NM*(NM-1)/2
#define HID 128
#define RANK 64
#define SDP_ITERS 100

// ---------------- ws layout (floats) ----------------
#define OFF_S      0
#define OFF_SUMW2  1600
#define OFF_BAR    1632        // 2 ints (barrier counter + generation), zeroed each launch
#define OFF_CVEC   1664
#define OFF_W1S    1792
#define OFF_WVEC   6912
#define OFF_WMAT   726400
#define OFF_VA     2166400
#define OFF_VB     2243200

__device__ __forceinline__ float wave_reduce_sum(float v) {
#pragma unroll
    for (int o = 32; o > 0; o >>= 1) v += __shfl_xor(v, o, 64);
    return v;
}

__global__ __launch_bounds__(256) void zero_kernel(float* __restrict__ ws, int n) {
    int i = blockIdx.x * 256 + threadIdx.x;
    if (i < n) ws[i] = 0.0f;
}

// ---- pass 1: S[40x40] = [x | 1]^T [x | 1] ----
// Double-buffered tiles; per-thread (row, col-chunk) staging map computed once
// (no div/mod/branch in the hot loop); loads issued into registers BEFORE the
// compute phase so HBM latency hides under the 360 FMAs/wave of the frag loop.
#define STATS_BLOCKS 1024
#define KT 40                      // k-rows per tile
__global__ __launch_bounds__(256) void stats_kernel(const float* __restrict__ x,
                                                    float* __restrict__ S) {
    __shared__ __align__(16) float tile[2][KT * 48];
    __shared__ float Sacc[48 * 48];
    const int tid = threadIdx.x;
    for (int i = tid; i < 48 * 48; i += 256) Sacc[i] = 0.f;
    // pad columns 40..47 are zero forever (never rewritten)
    for (int i = tid; i < 2 * KT * 8; i += 256) {
        int b = i / (KT * 8);
        int rem = i - b * (KT * 8);
        int r = rem >> 3, k = rem & 7;
        tile[b][r * 48 + 40 + k] = 0.f;
    }

    const int rpb = (PP + STATS_BLOCKS - 1) / STATS_BLOCKS;  // 703
    const int r0 = blockIdx.x * rpb;
    const int r1 = min(r0 + rpb, PP);

    // staging map: 200 threads, thread -> (row sr, col-chunk sc of 8)
    const bool stg = tid < 200;
    const int sr = tid / 5;                 // 0..39 (junk >=200, never used)
    const int sc = (tid - sr * 5) * 8;      // 0,8,16,24,32
    float* const dA = &tile[0][sr * 48 + sc];
    float* const dB = &tile[1][sr * 48 + sc];
    const float* const srcb = x + (size_t)sr * 39 + sc;
    const bool tail = (sc == 32);           // chunk 4: cols 32..38 + bias col 39

    const int z  = tid >> 6;                // wave id 0..3 -> k offset
    const int ln = tid & 63;
    const int ty = ln >> 3, tx = ln & 7;

    float acc[6][6];
#pragma unroll
    for (int a = 0; a < 6; ++a)
#pragma unroll
        for (int b = 0; b < 6; ++b) acc[a][b] = 0.f;

    float v[8];
    {   // prologue: load first tile
        const float* s = srcb + (size_t)r0 * 39;
        const bool ok = stg && (r0 + sr < r1);
#pragma unroll
        for (int k = 0; k < 8; ++k) v[k] = 0.f;
        if (ok) {
#pragma unroll
            for (int k = 0; k < 7; ++k) v[k] = s[k];
            v[7] = tail ? 1.0f : s[7];
        }
    }
    if (stg) {
        *(float4*)dA       = make_float4(v[0], v[1], v[2], v[3]);
        *(float4*)(dA + 4) = make_float4(v[4], v[5], v[6], v[7]);
    }
    __syncthreads();

    int cur = 0;
    for (int t = r0; t < r1; t += KT) {
        const int tn = t + KT;
        const bool more = tn < r1;          // uniform across block
        float vn[8];
        if (more) {                         // issue next tile's loads now
            const float* s = srcb + (size_t)tn * 39;
            const bool ok = stg && (tn + sr < r1);
#pragma unroll
            for (int k = 0; k < 8; ++k) vn[k] = 0.f;
            if (ok) {
#pragma unroll
                for (int k = 0; k < 7; ++k) vn[k] = s[k];
                vn[7] = tail ? 1.0f : s[7];
            }
        }
        // compute current tile (hides the loads above)
        const float* tb = tile[cur];
#pragma unroll 2
        for (int kk = 0; kk < KT / 4; ++kk) {
            const float* row = &tb[(kk * 4 + z) * 48];
            float2 a0 = *(const float2*)(row + ty * 6);
            float2 a1 = *(const float2*)(row + ty * 6 + 2);
            float2 a2 = *(const float2*)(row + ty * 6 + 4);
            float2 b0 = *(const float2*)(row + tx * 6);
            float2 b1 = *(const float2*)(row + tx * 6 + 2);
            float2 b2 = *(const float2*)(row + tx * 6 + 4);
            float av[6] = {a0.x, a0.y, a1.x, a1.y, a2.x, a2.y};
            float bv[6] = {b0.x, b0.y, b1.x, b1.y, b2.x, b2.y};
#pragma unroll
            for (int a = 0; a < 6; ++a)
#pragma unroll
                for (int b = 0; b < 6; ++b)
                    acc[a][b] = fmaf(av[a], bv[b], acc[a][b]);
        }
        if (more && stg) {                  // write next tile into the other buffer
            float* d = cur ? dA : dB;
            *(float4*)d       = make_float4(vn[0], vn[1], vn[2], vn[3]);
            *(float4*)(d + 4) = make_float4(vn[4], vn[5], vn[6], vn[7]);
        }
        __syncthreads();
        cur ^= 1;
    }

#pragma unroll
    for (int a = 0; a < 6; ++a)
#pragma unroll
        for (int b = 0; b < 6; ++b)
            atomicAdd(&Sacc[(ty * 6 + a) * 48 + tx * 6 + b], acc[a][b]);
    __syncthreads();
    for (int i = tid; i < 1600; i += 256) {
        int r = i / 40, c = i - r * 40;
        atomicAdd(&S[i], Sacc[r * 48 + c]);
    }
}

// ---- BN folding ----
__global__ __launch_bounds__(64) void bn_prep(const float* __restrict__ S,
                                              const float* __restrict__ W1,
                                              const float* __restrict__ gamma,
                                              const float* __restrict__ beta,
                                              float* __restrict__ W1s,
                                              float* __restrict__ cvec) {
    const int j = blockIdx.x;
    const int l = threadIdx.x;
    const float invP = 1.0f / (float)PP;
    float q = 0.f;
    for (int idx = l; idx < 39 * 39; idx += 64) {
        int a = idx / 39, b = idx - a * 39;
        q = fmaf(S[a * 40 + b], W1[a * HID + j] * W1[b * HID + j], q);
    }
    float s1 = (l < 39) ? (S[39 * 40 + l] * invP) * W1[l * HID + j] : 0.f;
    q = wave_reduce_sum(q);
    s1 = wave_reduce_sum(s1);
    float var = q * invP - s1 * s1;
    float scale = gamma[j] * (1.0f / sqrtf(var + 1e-5f));
    for (int a = l; a < 39; a += 64) W1s[a * HID + j] = W1[a * HID + j] * scale;
    if (l == 0) cvec[j] = -s1 * scale + beta[j];
}

// ---- fused MLP: xr[39] in registers, 2x64 strip-mine, inner loop s_load+FMA only ----
__global__ __launch_bounds__(256) void mlp_kernel(const float* __restrict__ x,
                                                  const float* __restrict__ W1s,
                                                  const float* __restrict__ cvec,
                                                  const float* __restrict__ W2,
                                                  const float* __restrict__ b2,
                                                  float* __restrict__ w,
                                                  float* __restrict__ sumw2) {
    __shared__ float xt[256 * 39];
    __shared__ float red[4];
    const size_t base = (size_t)blockIdx.x * 256;
    {
        const size_t g0 = base * 39;
        const size_t gmax = (size_t)PP * 39;
        for (int idx = threadIdx.x; idx < 256 * 39; idx += 256) {
            size_t g = g0 + idx;
            xt[idx] = (g < gmax) ? x[g] : 0.f;
        }
    }
    __syncthreads();

    float xr[39];
    {
        const float* xrow = &xt[threadIdx.x * 39];
#pragma unroll
        for (int k = 0; k < 39; ++k) xr[k] = xrow[k];
    }

    float wacc = 0.f;
#pragma unroll 1
    for (int c = 0; c < 2; ++c) {
        float acc[64];
#pragma unroll
        for (int jj = 0; jj < 64; ++jj) acc[jj] = cvec[c * 64 + jj];
#pragma unroll 3
        for (int k = 0; k < 39; ++k) {
            const float xk = xr[k];
            const float* wrow = &W1s[k * HID + c * 64];
#pragma unroll
            for (int jj = 0; jj < 64; ++jj) acc[jj] = fmaf(xk, wrow[jj], acc[jj]);
        }
#pragma unroll
        for (int jj = 0; jj < 64; ++jj)
            wacc = fmaf(fmaxf(acc[jj], 0.f), W2[c * 64 + jj], wacc);
    }

    const size_t p = base + threadIdx.x;
    const float wv = wacc + b2[0];
    float sq = 0.f;
    if (p < (size_t)PP) { w[p] = wv; sq = wv * wv; }
    sq = wave_reduce_sum(sq);
    if ((threadIdx.x & 63) == 0) red[threadIdx.x >> 6] = sq;
    __syncthreads();
    if (threadIdx.x == 0) atomicAdd(sumw2, red[0] + red[1] + red[2] + red[3]);
}

// ---- W build ----
__global__ __launch_bounds__(256) void buildW(const float* __restrict__ w,
                                              float* __restrict__ W) {
    __shared__ float tile[16][17];
    const int bi = blockIdx.y, bj = blockIdx.x;
    if (bi > bj) return;
    const int ty = threadIdx.x >> 4, tx = threadIdx.x & 15;
    const int i = bi * 16 + ty, j = bj * 16 + tx;
    float v = 0.f;
    if (i < j) {
        int p = i * (NM - 1) - (i * (i - 1)) / 2 + (j - i - 1);
        v = w[p];
    }
    tile[ty][tx] = v;
    __syncthreads();
    if (bi == bj) {
        float out = (i < j) ? v : ((i > j) ? tile[tx][ty] : 0.f);
        W[(size_t)i * NM + j] = out;
    } else {
        W[(size_t)i * NM + j] = v;
        W[(size_t)(bj * 16 + ty) * NM + (bi * 16 + tx)] = tile[tx][ty];
    }
}

// ---- V = V0 / ||row|| ----
__global__ __launch_bounds__(256) void v0norm(const float* __restrict__ V0,
                                              float* __restrict__ V) {
    const int i = blockIdx.x * 4 + (threadIdx.x >> 6);
    const int c = threadIdx.x & 63;
    float v = V0[(size_t)i * RANK + c];
    float s = wave_reduce_sum(v * v);
    V[(size_t)i * RANK + c] = v * (1.0f / sqrtf(s));
}

// ---- persistent SDP: ALL 100 iterations in ONE dispatch ----
// 240 blocks x 512 threads (5 rows/block, 8 waves = K/8 j-chunks of 150).
// Grid-wide generation barrier with agent-scope atomics between iterations.
// Co-residency: 240 blocks x 8 waves = 1920 waves << 256 CUs x 32 waves.
// Same per-row arithmetic/order as the old sdp_step -> identical numerics.
#define SDP_BLOCKS 240
#define ROWS_PB 5
__global__ __launch_bounds__(512) void sdp_persist(float* __restrict__ Va,
                                                   float* __restrict__ Vb,
                                                   const float* __restrict__ W,
                                                   const float* __restrict__ sumw2,
                                                   int* bar) {
    __shared__ float part[8][ROWS_PB][64];   // 10 KB
    const int tid = threadIdx.x;
    const int c = tid & 63;
    const int wvid = tid >> 6;                      // 0..7
    const int i0 = blockIdx.x * ROWS_PB;
    const int j0 = __builtin_amdgcn_readfirstlane(wvid * 150);
    const float lr = 1.0f / (sqrtf(2.0f * sumw2[0]) + 1e-8f);
    const float* __restrict__ Wb = W + (size_t)i0 * NM + j0;

    for (int it = 0; it < SDP_ITERS; ++it) {
        const float* __restrict__ Vin = (it & 1) ? Vb : Va;
        float* __restrict__ Vout      = (it & 1) ? Va : Vb;
        const float* __restrict__ Vbase = Vin + (size_t)j0 * RANK + c;

        float acc[ROWS_PB] = {0.f, 0.f, 0.f, 0.f, 0.f};
#pragma unroll 10
        for (int t = 0; t < 150; ++t) {
            const float vc = Vbase[(size_t)t * RANK];
#pragma unroll
            for (int r = 0; r < ROWS_PB; ++r)
                acc[r] = fmaf(Wb[(size_t)r * NM + t], vc, acc[r]);
        }
#pragma unroll
        for (int r = 0; r < ROWS_PB; ++r) part[wvid][r][c] = acc[r];
        __syncthreads();

        if (tid < ROWS_PB * 64) {
            const int r2 = tid >> 6, c2 = tid & 63;
            float s = 0.f;
#pragma unroll
            for (int k = 0; k < 8; ++k) s += part[k][r2][c2];
            float y = Vin[(size_t)(i0 + r2) * RANK + c2] + lr * s;
            float n = wave_reduce_sum(y * y);
            Vout[(size_t)(i0 + r2) * RANK + c2] = y * (1.0f / sqrtf(n));
        }

        // ---- grid barrier (generation counter, agent scope) ----
        __syncthreads();
        if (tid == 0) {
            __threadfence();   // publish this block's Vout to agent scope
            if (__hip_atomic_fetch_add(&bar[0], 1, __ATOMIC_ACQ_REL,
                                       __HIP_MEMORY_SCOPE_AGENT) == SDP_BLOCKS - 1) {
                __hip_atomic_store(&bar[0], 0, __ATOMIC_RELAXED, __HIP_MEMORY_SCOPE_AGENT);
                __hip_atomic_store(&bar[1], it + 1, __ATOMIC_RELEASE, __HIP_MEMORY_SCOPE_AGENT);
            } else {
                while (__hip_atomic_load(&bar[1], __ATOMIC_ACQUIRE,
                                         __HIP_MEMORY_SCOPE_AGENT) <= it) {
                    __builtin_amdgcn_s_sleep(1);
                }
            }
        }
        __syncthreads();
    }
}

// ---- out = clip(V V^T, 0, 1): 128x128 symmetric tiles, 8x8 frags ----
__global__ __launch_bounds__(256) void vvt_kernel(const float* __restrict__ V,
                                                  float* __restrict__ out) {
    const int bi = blockIdx.y, bj = blockIdx.x;
    if (bi > bj) return;
    __shared__ __align__(16) float Ti[64][132];   // [k][row]
    __shared__ __align__(16) float Tj[64][132];
    const int tid = threadIdx.x;
    for (int idx = tid; idx < 128 * 64; idx += 256) {
        int row = idx >> 6, k = idx & 63;
        int gi = bi * 128 + row, gj = bj * 128 + row;
        Ti[k][row] = (gi < NM) ? V[(size_t)gi * RANK + k] : 0.f;
        Tj[k][row] = (gj < NM) ? V[(size_t)gj * RANK + k] : 0.f;
    }
    __syncthreads();
    const int ty = tid >> 4, tx = tid & 15;
    float acc[8][8];
#pragma unroll
    for (int a = 0; a < 8; ++a)
#pragma unroll
        for (int b = 0; b < 8; ++b) acc[a][b] = 0.f;
    for (int k = 0; k < 64; ++k) {
        float4 a0 = *(const float4*)&Ti[k][ty * 8];
        float4 a1 = *(const float4*)&Ti[k][ty * 8 + 4];
        float4 b0 = *(const float4*)&Tj[k][tx * 8];
        float4 b1 = *(const float4*)&Tj[k][tx * 8 + 4];
        float av[8] = {a0.x, a0.y, a0.z, a0.w, a1.x, a1.y, a1.z, a1.w};
        float bv[8] = {b0.x, b0.y, b0.z, b0.w, b1.x, b1.y, b1.z, b1.w};
#pragma unroll
        for (int a = 0; a < 8; ++a)
#pragma unroll
            for (int b = 0; b < 8; ++b)
                acc[a][b] = fmaf(av[a], bv[b], acc[a][b]);
    }
#pragma unroll
    for (int a = 0; a < 8; ++a) {
        int i = bi * 128 + 8 * ty + a;
        if (i >= NM) break;
        int jb = bj * 128 + 8 * tx;
        if (jb + 7 < NM) {
            float4 s0 = {fminf(fmaxf(acc[a][0], 0.f), 1.f), fminf(fmaxf(acc[a][1], 0.f), 1.f),
                         fminf(fmaxf(acc[a][2], 0.f), 1.f), fminf(fmaxf(acc[a][3], 0.f), 1.f)};
            float4 s1 = {fminf(fmaxf(acc[a][4], 0.f), 1.f), fminf(fmaxf(acc[a][5], 0.f), 1.f),
                         fminf(fmaxf(acc[a][6], 0.f), 1.f), fminf(fmaxf(acc[a][7], 0.f), 1.f)};
            *(float4*)&out[(size_t)i * NM + jb] = s0;
            *(float4*)&out[(size_t)i * NM + jb + 4] = s1;
        } else {
#pragma unroll
            for (int b = 0; b < 8; ++b) {
                int j = jb + b;
                if (j < NM) out[(size_t)i * NM + j] = fminf(fmaxf(acc[a][b], 0.f), 1.f);
            }
        }
    }
    if (bi != bj) {
#pragma unroll
        for (int b = 0; b < 8; ++b) {
            int j = bj * 128 + 8 * tx + b;
            if (j >= NM) break;
            int ib = bi * 128 + 8 * ty;
            if (ib + 7 < NM) {
                float4 s0 = {fminf(fmaxf(acc[0][b], 0.f), 1.f), fminf(fmaxf(acc[1][b], 0.f), 1.f),
                             fminf(fmaxf(acc[2][b], 0.f), 1.f), fminf(fmaxf(acc[3][b], 0.f), 1.f)};
                float4 s1 = {fminf(fmaxf(acc[4][b], 0.f), 1.f), fminf(fmaxf(acc[5][b], 0.f), 1.f),
                             fminf(fmaxf(acc[6][b], 0.f), 1.f), fminf(fmaxf(acc[7][b], 0.f), 1.f)};
                *(float4*)&out[(size_t)j * NM + ib] = s0;
                *(float4*)&out[(size_t)j * NM + ib + 4] = s1;
            } else {
#pragma unroll
                for (int a = 0; a < 8; ++a) {
                    int i = ib + a;
                    if (i < NM) out[(size_t)j * NM + i] = fminf(fmaxf(acc[a][b], 0.f), 1.f);
                }
            }
        }
    }
}

extern "C" void kernel_launch(void* const* d_in, const int* in_sizes, int n_in,
                              void* d_out, int out_size, void* d_ws, size_t ws_size,
                              hipStream_t stream) {
    const float* x     = (const float*)d_in[0];
    const float* W1    = (const float*)d_in[1];
    const float* gamma = (const float*)d_in[3];
    const float* beta  = (const float*)d_in[4];
    const float* W2    = (const float*)d_in[5];
    const float* b2    = (const float*)d_in[6];
    const float* V0    = (const float*)d_in[7];
    float* out = (float*)d_out;

    float* ws    = (float*)d_ws;
    float* S     = ws + OFF_S;
    float* sumw2 = ws + OFF_SUMW2;
    float* cvec  = ws + OFF_CVEC;
    float* W1s   = ws + OFF_W1S;
    float* wvec  = ws + OFF_WVEC;
    float* Wmat  = ws + OFF_WMAT;
    float* Va    = ws + OFF_VA;
    float* Vb    = ws + OFF_VB;

    zero_kernel<<<7, 256, 0, stream>>>(ws, OFF_W1S);   // S + sumw2 + barrier
    stats_kernel<<<STATS_BLOCKS, 256, 0, stream>>>(x, S);
    bn_prep<<<HID, 64, 0, stream>>>(S, W1, gamma, beta, W1s, cvec);
    mlp_kernel<<<(PP + 255) / 256, 256, 0, stream>>>(x, W1s, cvec, W2, b2, wvec, sumw2);
    buildW<<<dim3(75, 75), 256, 0, stream>>>(wvec, Wmat);
    v0norm<<<NM / 4, 256, 0, stream>>>(V0, Va);
    // all 100 SDP iterations in one persistent dispatch; final V lands in Va
    // (iteration 99 is odd -> writes Va, same parity as the old loop)
    sdp_persist<<<SDP_BLOCKS, 512, 0, stream>>>(Va, Vb, Wmat, sumw2, (int*)(ws + OFF_BAR));
    vvt_kernel<<<dim3(10, 10), 256, 0, stream>>>(Va, out);
}

// Round 2
// 1187.948 us; speedup vs baseline: 2.5000x; 2.5000x over previous
//
#include <hip/hip_runtime.h>

#define NM 1200
#define PP 719400      // NM*(NM-1)/2
#define HID 128
#define RANK 64
#define SDP_ITERS 100

// ---------------- ws layout (floats) ----------------
#define OFF_S      0
#define OFF_SUMW2  1600
#define OFF_CVEC   1664
#define OFF_W1S    1792
#define OFF_WVEC   6912
#define OFF_WMAT   726400
#define OFF_VA     2166400
#define OFF_VB     2243200

__device__ __forceinline__ float wave_reduce_sum(float v) {
#pragma unroll
    for (int o = 32; o > 0; o >>= 1) v += __shfl_xor(v, o, 64);
    return v;
}

__global__ __launch_bounds__(256) void zero_kernel(float* __restrict__ ws, int n) {
    int i = blockIdx.x * 256 + threadIdx.x;
    if (i < n) ws[i] = 0.0f;
}

// ---- pass 1: S[40x40] = [x | 1]^T [x | 1] ----
// Double-buffered tiles; per-thread (row, col-chunk) staging map computed once;
// loads issued into registers BEFORE the compute phase so HBM latency hides
// under the 360 FMAs/wave of the frag loop.
#define STATS_BLOCKS 1024
#define KT 40                      // k-rows per tile
__global__ __launch_bounds__(256) void stats_kernel(const float* __restrict__ x,
                                                    float* __restrict__ S) {
    __shared__ __align__(16) float tile[2][KT * 48];
    __shared__ float Sacc[48 * 48];
    const int tid = threadIdx.x;
    for (int i = tid; i < 48 * 48; i += 256) Sacc[i] = 0.f;
    // pad columns 40..47 are zero forever (never rewritten)
    for (int i = tid; i < 2 * KT * 8; i += 256) {
        int b = i / (KT * 8);
        int rem = i - b * (KT * 8);
        int r = rem >> 3, k = rem & 7;
        tile[b][r * 48 + 40 + k] = 0.f;
    }

    const int rpb = (PP + STATS_BLOCKS - 1) / STATS_BLOCKS;  // 703
    const int r0 = blockIdx.x * rpb;
    const int r1 = min(r0 + rpb, PP);

    // staging map: 200 threads, thread -> (row sr, col-chunk sc of 8)
    const bool stg = tid < 200;
    const int sr = tid / 5;                 // 0..39 (junk >=200, never used)
    const int sc = (tid - sr * 5) * 8;      // 0,8,16,24,32
    float* const dA = &tile[0][sr * 48 + sc];
    float* const dB = &tile[1][sr * 48 + sc];
    const float* const srcb = x + (size_t)sr * 39 + sc;
    const bool tail = (sc == 32);           // chunk 4: cols 32..38 + bias col 39

    const int z  = tid >> 6;                // wave id 0..3 -> k offset
    const int ln = tid & 63;
    const int ty = ln >> 3, tx = ln & 7;

    float acc[6][6];
#pragma unroll
    for (int a = 0; a < 6; ++a)
#pragma unroll
        for (int b = 0; b < 6; ++b) acc[a][b] = 0.f;

    float v[8];
    {   // prologue: load first tile
        const float* s = srcb + (size_t)r0 * 39;
        const bool ok = stg && (r0 + sr < r1);
#pragma unroll
        for (int k = 0; k < 8; ++k) v[k] = 0.f;
        if (ok) {
#pragma unroll
            for (int k = 0; k < 7; ++k) v[k] = s[k];
            v[7] = tail ? 1.0f : s[7];
        }
    }
    if (stg) {
        *(float4*)dA       = make_float4(v[0], v[1], v[2], v[3]);
        *(float4*)(dA + 4) = make_float4(v[4], v[5], v[6], v[7]);
    }
    __syncthreads();

    int cur = 0;
    for (int t = r0; t < r1; t += KT) {
        const int tn = t + KT;
        const bool more = tn < r1;          // uniform across block
        float vn[8];
        if (more) {                         // issue next tile's loads now
            const float* s = srcb + (size_t)tn * 39;
            const bool ok = stg && (tn + sr < r1);
#pragma unroll
            for (int k = 0; k < 8; ++k) vn[k] = 0.f;
            if (ok) {
#pragma unroll
                for (int k = 0; k < 7; ++k) vn[k] = s[k];
                vn[7] = tail ? 1.0f : s[7];
            }
        }
        // compute current tile (hides the loads above)
        const float* tb = tile[cur];
#pragma unroll 2
        for (int kk = 0; kk < KT / 4; ++kk) {
            const float* row = &tb[(kk * 4 + z) * 48];
            float2 a0 = *(const float2*)(row + ty * 6);
            float2 a1 = *(const float2*)(row + ty * 6 + 2);
            float2 a2 = *(const float2*)(row + ty * 6 + 4);
            float2 b0 = *(const float2*)(row + tx * 6);
            float2 b1 = *(const float2*)(row + tx * 6 + 2);
            float2 b2 = *(const float2*)(row + tx * 6 + 4);
            float av[6] = {a0.x, a0.y, a1.x, a1.y, a2.x, a2.y};
            float bv[6] = {b0.x, b0.y, b1.x, b1.y, b2.x, b2.y};
#pragma unroll
            for (int a = 0; a < 6; ++a)
#pragma unroll
                for (int b = 0; b < 6; ++b)
                    acc[a][b] = fmaf(av[a], bv[b], acc[a][b]);
        }
        if (more && stg) {                  // write next tile into the other buffer
            float* d = cur ? dA : dB;
            *(float4*)d       = make_float4(vn[0], vn[1], vn[2], vn[3]);
            *(float4*)(d + 4) = make_float4(vn[4], vn[5], vn[6], vn[7]);
        }
        __syncthreads();
        cur ^= 1;
    }

#pragma unroll
    for (int a = 0; a < 6; ++a)
#pragma unroll
        for (int b = 0; b < 6; ++b)
            atomicAdd(&Sacc[(ty * 6 + a) * 48 + tx * 6 + b], acc[a][b]);
    __syncthreads();
    for (int i = tid; i < 1600; i += 256) {
        int r = i / 40, c = i - r * 40;
        atomicAdd(&S[i], Sacc[r * 48 + c]);
    }
}

// ---- BN folding ----
__global__ __launch_bounds__(64) void bn_prep(const float* __restrict__ S,
                                              const float* __restrict__ W1,
                                              const float* __restrict__ gamma,
                                              const float* __restrict__ beta,
                                              float* __restrict__ W1s,
                                              float* __restrict__ cvec) {
    const int j = blockIdx.x;
    const int l = threadIdx.x;
    const float invP = 1.0f / (float)PP;
    float q = 0.f;
    for (int idx = l; idx < 39 * 39; idx += 64) {
        int a = idx / 39, b = idx - a * 39;
        q = fmaf(S[a * 40 + b], W1[a * HID + j] * W1[b * HID + j], q);
    }
    float s1 = (l < 39) ? (S[39 * 40 + l] * invP) * W1[l * HID + j] : 0.f;
    q = wave_reduce_sum(q);
    s1 = wave_reduce_sum(s1);
    float var = q * invP - s1 * s1;
    float scale = gamma[j] * (1.0f / sqrtf(var + 1e-5f));
    for (int a = l; a < 39; a += 64) W1s[a * HID + j] = W1[a * HID + j] * scale;
    if (l == 0) cvec[j] = -s1 * scale + beta[j];
}

// ---- fused MLP: xr[39] in registers, 2x64 strip-mine, inner loop s_load+FMA only ----
__global__ __launch_bounds__(256) void mlp_kernel(const float* __restrict__ x,
                                                  const float* __restrict__ W1s,
                                                  const float* __restrict__ cvec,
                                                  const float* __restrict__ W2,
                                                  const float* __restrict__ b2,
                                                  float* __restrict__ w,
                                                  float* __restrict__ sumw2) {
    __shared__ float xt[256 * 39];
    __shared__ float red[4];
    const size_t base = (size_t)blockIdx.x * 256;
    {
        const size_t g0 = base * 39;
        const size_t gmax = (size_t)PP * 39;
        for (int idx = threadIdx.x; idx < 256 * 39; idx += 256) {
            size_t g = g0 + idx;
            xt[idx] = (g < gmax) ? x[g] : 0.f;
        }
    }
    __syncthreads();

    float xr[39];
    {
        const float* xrow = &xt[threadIdx.x * 39];
#pragma unroll
        for (int k = 0; k < 39; ++k) xr[k] = xrow[k];
    }

    float wacc = 0.f;
#pragma unroll 1
    for (int c = 0; c < 2; ++c) {
        float acc[64];
#pragma unroll
        for (int jj = 0; jj < 64; ++jj) acc[jj] = cvec[c * 64 + jj];
#pragma unroll 3
        for (int k = 0; k < 39; ++k) {
            const float xk = xr[k];
            const float* wrow = &W1s[k * HID + c * 64];
#pragma unroll
            for (int jj = 0; jj < 64; ++jj) acc[jj] = fmaf(xk, wrow[jj], acc[jj]);
        }
#pragma unroll
        for (int jj = 0; jj < 64; ++jj)
            wacc = fmaf(fmaxf(acc[jj], 0.f), W2[c * 64 + jj], wacc);
    }

    const size_t p = base + threadIdx.x;
    const float wv = wacc + b2[0];
    float sq = 0.f;
    if (p < (size_t)PP) { w[p] = wv; sq = wv * wv; }
    sq = wave_reduce_sum(sq);
    if ((threadIdx.x & 63) == 0) red[threadIdx.x >> 6] = sq;
    __syncthreads();
    if (threadIdx.x == 0) atomicAdd(sumw2, red[0] + red[1] + red[2] + red[3]);
}

// ---- W build ----
__global__ __launch_bounds__(256) void buildW(const float* __restrict__ w,
                                              float* __restrict__ W) {
    __shared__ float tile[16][17];
    const int bi = blockIdx.y, bj = blockIdx.x;
    if (bi > bj) return;
    const int ty = threadIdx.x >> 4, tx = threadIdx.x & 15;
    const int i = bi * 16 + ty, j = bj * 16 + tx;
    float v = 0.f;
    if (i < j) {
        int p = i * (NM - 1) - (i * (i - 1)) / 2 + (j - i - 1);
        v = w[p];
    }
    tile[ty][tx] = v;
    __syncthreads();
    if (bi == bj) {
        float out = (i < j) ? v : ((i > j) ? tile[tx][ty] : 0.f);
        W[(size_t)i * NM + j] = out;
    } else {
        W[(size_t)i * NM + j] = v;
        W[(size_t)(bj * 16 + ty) * NM + (bi * 16 + tx)] = tile[tx][ty];
    }
}

// ---- V = V0 / ||row|| ----
__global__ __launch_bounds__(256) void v0norm(const float* __restrict__ V0,
                                              float* __restrict__ V) {
    const int i = blockIdx.x * 4 + (threadIdx.x >> 6);
    const int c = threadIdx.x & 63;
    float v = V0[(size_t)i * RANK + c];
    float s = wave_reduce_sum(v * v);
    V[(size_t)i * RANK + c] = v * (1.0f / sqrtf(s));
}

// ---- one SDP step: Vout = rownorm(Vin + lr * W @ Vin) ----
// 240 blocks x 512 threads (8 waves). Block owns 5 rows; wave = j-chunk of 150;
// lane = rank column. W via wave-uniform scalar loads; V via coalesced 256B loads.
// V stream is software-pipelined through 3 named 30-deep register buffers so
// 60-90 loads stay in flight (old version: ~10 -> latency-bound at ~2 waves/SIMD).
// FMA order per acc[r] is strict t=0..149 -> bitwise-identical numerics.
#define SDP_BLOCKS 240
#define ROWS_PB 5
#define VU 30

__device__ __forceinline__ void sdp_loadv(float* buf, const float* __restrict__ Vb, int tb) {
#pragma unroll
    for (int u = 0; u < VU; ++u) buf[u] = Vb[(size_t)(tb + u) * RANK];
}

__device__ __forceinline__ void sdp_fmav(float* acc, const float* buf,
                                         const float* __restrict__ Wb, int tb) {
#pragma unroll
    for (int u = 0; u < VU; ++u) {
#pragma unroll
        for (int r = 0; r < ROWS_PB; ++r)
            acc[r] = fmaf(Wb[(size_t)r * NM + tb + u], buf[u], acc[r]);
    }
}

__global__ __launch_bounds__(512) void sdp_step(const float* __restrict__ Vin,
                                                float* __restrict__ Vout,
                                                const float* __restrict__ W,
                                                const float* __restrict__ sumw2) {
    __shared__ float part[8][ROWS_PB][64];   // 10 KB
    const int tid = threadIdx.x;
    const int c = tid & 63;
    const int wvid = tid >> 6;                      // 0..7
    const int i0 = blockIdx.x * ROWS_PB;
    const int j0 = __builtin_amdgcn_readfirstlane(wvid * 150);

    const float* __restrict__ Wb = W + (size_t)i0 * NM + j0;
    const float* __restrict__ Vb = Vin + (size_t)j0 * RANK + c;

    float acc[ROWS_PB] = {0.f, 0.f, 0.f, 0.f, 0.f};
    float va[VU], vb[VU], vc[VU];

    // pipelined 5 batches of 30: loads lead their consuming FMA group by >=2 batches
    sdp_loadv(va, Vb, 0);
    sdp_loadv(vb, Vb, 30);
    sdp_loadv(vc, Vb, 60);
    sdp_fmav(acc, va, Wb, 0);
    sdp_loadv(va, Vb, 90);          // WAR on va: issues after fmav(va) in program order
    sdp_fmav(acc, vb, Wb, 30);
    sdp_loadv(vb, Vb, 120);
    sdp_fmav(acc, vc, Wb, 60);
    sdp_fmav(acc, va, Wb, 90);
    sdp_fmav(acc, vb, Wb, 120);

#pragma unroll
    for (int r = 0; r < ROWS_PB; ++r) part[wvid][r][c] = acc[r];
    __syncthreads();

    if (tid < ROWS_PB * 64) {
        const int r2 = tid >> 6, c2 = tid & 63;
        float s = 0.f;
#pragma unroll
        for (int k = 0; k < 8; ++k) s += part[k][r2][c2];
        const float lr = 1.0f / (sqrtf(2.0f * sumw2[0]) + 1e-8f);
        float y = Vin[(size_t)(i0 + r2) * RANK + c2] + lr * s;
        float n = wave_reduce_sum(y * y);
        Vout[(size_t)(i0 + r2) * RANK + c2] = y * (1.0f / sqrtf(n));
    }
}

// ---- out = clip(V V^T, 0, 1): 128x128 symmetric tiles, 8x8 frags ----
__global__ __launch_bounds__(256) void vvt_kernel(const float* __restrict__ V,
                                                  float* __restrict__ out) {
    const int bi = blockIdx.y, bj = blockIdx.x;
    if (bi > bj) return;
    __shared__ __align__(16) float Ti[64][132];   // [k][row]
    __shared__ __align__(16) float Tj[64][132];
    const int tid = threadIdx.x;
    for (int idx = tid; idx < 128 * 64; idx += 256) {
        int row = idx >> 6, k = idx & 63;
        int gi = bi * 128 + row, gj = bj * 128 + row;
        Ti[k][row] = (gi < NM) ? V[(size_t)gi * RANK + k] : 0.f;
        Tj[k][row] = (gj < NM) ? V[(size_t)gj * RANK + k] : 0.f;
    }
    __syncthreads();
    const int ty = tid >> 4, tx = tid & 15;
    float acc[8][8];
#pragma unroll
    for (int a = 0; a < 8; ++a)
#pragma unroll
        for (int b = 0; b < 8; ++b) acc[a][b] = 0.f;
    for (int k = 0; k < 64; ++k) {
        float4 a0 = *(const float4*)&Ti[k][ty * 8];
        float4 a1 = *(const float4*)&Ti[k][ty * 8 + 4];
        float4 b0 = *(const float4*)&Tj[k][tx * 8];
        float4 b1 = *(const float4*)&Tj[k][tx * 8 + 4];
        float av[8] = {a0.x, a0.y, a0.z, a0.w, a1.x, a1.y, a1.z, a1.w};
        float bv[8] = {b0.x, b0.y, b0.z, b0.w, b1.x, b1.y, b1.z, b1.w};
#pragma unroll
        for (int a = 0; a < 8; ++a)
#pragma unroll
            for (int b = 0; b < 8; ++b)
                acc[a][b] = fmaf(av[a], bv[b], acc[a][b]);
    }
#pragma unroll
    for (int a = 0; a < 8; ++a) {
        int i = bi * 128 + 8 * ty + a;
        if (i >= NM) break;
        int jb = bj * 128 + 8 * tx;
        if (jb + 7 < NM) {
            float4 s0 = {fminf(fmaxf(acc[a][0], 0.f), 1.f), fminf(fmaxf(acc[a][1], 0.f), 1.f),
                         fminf(fmaxf(acc[a][2], 0.f), 1.f), fminf(fmaxf(acc[a][3], 0.f), 1.f)};
            float4 s1 = {fminf(fmaxf(acc[a][4], 0.f), 1.f), fminf(fmaxf(acc[a][5], 0.f), 1.f),
                         fminf(fmaxf(acc[a][6], 0.f), 1.f), fminf(fmaxf(acc[a][7], 0.f), 1.f)};
            *(float4*)&out[(size_t)i * NM + jb] = s0;
            *(float4*)&out[(size_t)i * NM + jb + 4] = s1;
        } else {
#pragma unroll
            for (int b = 0; b < 8; ++b) {
                int j = jb + b;
                if (j < NM) out[(size_t)i * NM + j] = fminf(fmaxf(acc[a][b], 0.f), 1.f);
            }
        }
    }
    if (bi != bj) {
#pragma unroll
        for (int b = 0; b < 8; ++b) {
            int j = bj * 128 + 8 * tx + b;
            if (j >= NM) break;
            int ib = bi * 128 + 8 * ty;
            if (ib + 7 < NM) {
                float4 s0 = {fminf(fmaxf(acc[0][b], 0.f), 1.f), fminf(fmaxf(acc[1][b], 0.f), 1.f),
                             fminf(fmaxf(acc[2][b], 0.f), 1.f), fminf(fmaxf(acc[3][b], 0.f), 1.f)};
                float4 s1 = {fminf(fmaxf(acc[4][b], 0.f), 1.f), fminf(fmaxf(acc[5][b], 0.f), 1.f),
                             fminf(fmaxf(acc[6][b], 0.f), 1.f), fminf(fmaxf(acc[7][b], 0.f), 1.f)};
                *(float4*)&out[(size_t)j * NM + ib] = s0;
                *(float4*)&out[(size_t)j * NM + ib + 4] = s1;
            } else {
#pragma unroll
                for (int a = 0; a < 8; ++a) {
                    int i = ib + a;
                    if (i < NM) out[(size_t)j * NM + i] = fminf(fmaxf(acc[a][b], 0.f), 1.f);
                }
            }
        }
    }
}

extern "C" void kernel_launch(void* const* d_in, const int* in_sizes, int n_in,
                              void* d_out, int out_size, void* d_ws, size_t ws_size,
                              hipStream_t stream) {
    const float* x     = (const float*)d_in[0];
    const float* W1    = (const float*)d_in[1];
    const float* gamma = (const float*)d_in[3];
    const float* beta  = (const float*)d_in[4];
    const float* W2    = (const float*)d_in[5];
    const float* b2    = (const float*)d_in[6];
    const float* V0    = (const float*)d_in[7];
    float* out = (float*)d_out;

    float* ws    = (float*)d_ws;
    float* S     = ws + OFF_S;
    float* sumw2 = ws + OFF_SUMW2;
    float* cvec  = ws + OFF_CVEC;
    float* W1s   = ws + OFF_W1S;
    float* wvec  = ws + OFF_WVEC;
    float* Wmat  = ws + OFF_WMAT;
    float* Va    = ws + OFF_VA;
    float* Vb    = ws + OFF_VB;

    zero_kernel<<<7, 256, 0, stream>>>(ws, OFF_W1S);   // S + sumw2
    stats_kernel<<<STATS_BLOCKS, 256, 0, stream>>>(x, S);
    bn_prep<<<HID, 64, 0, stream>>>(S, W1, gamma, beta, W1s, cvec);
    mlp_kernel<<<(PP + 255) / 256, 256, 0, stream>>>(x, W1s, cvec, W2, b2, wvec, sumw2);
    buildW<<<dim3(75, 75), 256, 0, stream>>>(wvec, Wmat);
    v0norm<<<NM / 4, 256, 0, stream>>>(V0, Va);
    for (int it = 0; it < SDP_ITERS; ++it) {
        const float* vin = (it & 1) ? Vb : Va;
        float* vout      = (it & 1) ? Va : Vb;
        sdp_step<<<SDP_BLOCKS, 512, 0, stream>>>(vin, vout, Wmat, sumw2);
    }
    // iter 99 (odd) writes Va
    vvt_kernel<<<dim3(10, 10), 256, 0, stream>>>(Va, out);
}

// Round 3
// 1182.099 us; speedup vs baseline: 2.5124x; 1.0049x over previous
//
#include <hip/hip_runtime.h>

#define NM 1200
#define PP 719400      // NM*(NM-1)/2
#define HID 128
#define RANK 64
#define SDP_ITERS 100

// ---------------- ws layout (floats) ----------------
#define OFF_S      0
#define OFF_SUMW2  1600
#define OFF_CVEC   1664
#define OFF_W1S    1792
#define OFF_WVEC   6912
#define OFF_WMAT   726400
#define OFF_VA     2166400
#define OFF_VB     2243200

__device__ __forceinline__ float wave_reduce_sum(float v) {
#pragma unroll
    for (int o = 32; o > 0; o >>= 1) v += __shfl_xor(v, o, 64);
    return v;
}

__global__ __launch_bounds__(256) void zero_kernel(float* __restrict__ ws, int n) {
    int i = blockIdx.x * 256 + threadIdx.x;
    if (i < n) ws[i] = 0.0f;
}

// ---- pass 1: S[40x40] = [x | 1]^T [x | 1] ----
// Double-buffered tiles; per-thread (row, col-chunk) staging map computed once;
// loads issued into registers BEFORE the compute phase so HBM latency hides
// under the 360 FMAs/wave of the frag loop.
#define STATS_BLOCKS 1024
#define KT 40                      // k-rows per tile
__global__ __launch_bounds__(256) void stats_kernel(const float* __restrict__ x,
                                                    float* __restrict__ S) {
    __shared__ __align__(16) float tile[2][KT * 48];
    __shared__ float Sacc[48 * 48];
    const int tid = threadIdx.x;
    for (int i = tid; i < 48 * 48; i += 256) Sacc[i] = 0.f;
    // pad columns 40..47 are zero forever (never rewritten)
    for (int i = tid; i < 2 * KT * 8; i += 256) {
        int b = i / (KT * 8);
        int rem = i - b * (KT * 8);
        int r = rem >> 3, k = rem & 7;
        tile[b][r * 48 + 40 + k] = 0.f;
    }

    const int rpb = (PP + STATS_BLOCKS - 1) / STATS_BLOCKS;  // 703
    const int r0 = blockIdx.x * rpb;
    const int r1 = min(r0 + rpb, PP);

    // staging map: 200 threads, thread -> (row sr, col-chunk sc of 8)
    const bool stg = tid < 200;
    const int sr = tid / 5;                 // 0..39 (junk >=200, never used)
    const int sc = (tid - sr * 5) * 8;      // 0,8,16,24,32
    float* const dA = &tile[0][sr * 48 + sc];
    float* const dB = &tile[1][sr * 48 + sc];
    const float* const srcb = x + (size_t)sr * 39 + sc;
    const bool tail = (sc == 32);           // chunk 4: cols 32..38 + bias col 39

    const int z  = tid >> 6;                // wave id 0..3 -> k offset
    const int ln = tid & 63;
    const int ty = ln >> 3, tx = ln & 7;

    float acc[6][6];
#pragma unroll
    for (int a = 0; a < 6; ++a)
#pragma unroll
        for (int b = 0; b < 6; ++b) acc[a][b] = 0.f;

    float v[8];
    {   // prologue: load first tile
        const float* s = srcb + (size_t)r0 * 39;
        const bool ok = stg && (r0 + sr < r1);
#pragma unroll
        for (int k = 0; k < 8; ++k) v[k] = 0.f;
        if (ok) {
#pragma unroll
            for (int k = 0; k < 7; ++k) v[k] = s[k];
            v[7] = tail ? 1.0f : s[7];
        }
    }
    if (stg) {
        *(float4*)dA       = make_float4(v[0], v[1], v[2], v[3]);
        *(float4*)(dA + 4) = make_float4(v[4], v[5], v[6], v[7]);
    }
    __syncthreads();

    int cur = 0;
    for (int t = r0; t < r1; t += KT) {
        const int tn = t + KT;
        const bool more = tn < r1;          // uniform across block
        float vn[8];
        if (more) {                         // issue next tile's loads now
            const float* s = srcb + (size_t)tn * 39;
            const bool ok = stg && (tn + sr < r1);
#pragma unroll
            for (int k = 0; k < 8; ++k) vn[k] = 0.f;
            if (ok) {
#pragma unroll
                for (int k = 0; k < 7; ++k) vn[k] = s[k];
                vn[7] = tail ? 1.0f : s[7];
            }
        }
        // compute current tile (hides the loads above)
        const float* tb = tile[cur];
#pragma unroll 2
        for (int kk = 0; kk < KT / 4; ++kk) {
            const float* row = &tb[(kk * 4 + z) * 48];
            float2 a0 = *(const float2*)(row + ty * 6);
            float2 a1 = *(const float2*)(row + ty * 6 + 2);
            float2 a2 = *(const float2*)(row + ty * 6 + 4);
            float2 b0 = *(const float2*)(row + tx * 6);
            float2 b1 = *(const float2*)(row + tx * 6 + 2);
            float2 b2 = *(const float2*)(row + tx * 6 + 4);
            float av[6] = {a0.x, a0.y, a1.x, a1.y, a2.x, a2.y};
            float bv[6] = {b0.x, b0.y, b1.x, b1.y, b2.x, b2.y};
#pragma unroll
            for (int a = 0; a < 6; ++a)
#pragma unroll
                for (int b = 0; b < 6; ++b)
                    acc[a][b] = fmaf(av[a], bv[b], acc[a][b]);
        }
        if (more && stg) {                  // write next tile into the other buffer
            float* d = cur ? dA : dB;
            *(float4*)d       = make_float4(vn[0], vn[1], vn[2], vn[3]);
            *(float4*)(d + 4) = make_float4(vn[4], vn[5], vn[6], vn[7]);
        }
        __syncthreads();
        cur ^= 1;
    }

#pragma unroll
    for (int a = 0; a < 6; ++a)
#pragma unroll
        for (int b = 0; b < 6; ++b)
            atomicAdd(&Sacc[(ty * 6 + a) * 48 + tx * 6 + b], acc[a][b]);
    __syncthreads();
    for (int i = tid; i < 1600; i += 256) {
        int r = i / 40, c = i - r * 40;
        atomicAdd(&S[i], Sacc[r * 48 + c]);
    }
}

// ---- BN folding ----
__global__ __launch_bounds__(64) void bn_prep(const float* __restrict__ S,
                                              const float* __restrict__ W1,
                                              const float* __restrict__ gamma,
                                              const float* __restrict__ beta,
                                              float* __restrict__ W1s,
                                              float* __restrict__ cvec) {
    const int j = blockIdx.x;
    const int l = threadIdx.x;
    const float invP = 1.0f / (float)PP;
    float q = 0.f;
    for (int idx = l; idx < 39 * 39; idx += 64) {
        int a = idx / 39, b = idx - a * 39;
        q = fmaf(S[a * 40 + b], W1[a * HID + j] * W1[b * HID + j], q);
    }
    float s1 = (l < 39) ? (S[39 * 40 + l] * invP) * W1[l * HID + j] : 0.f;
    q = wave_reduce_sum(q);
    s1 = wave_reduce_sum(s1);
    float var = q * invP - s1 * s1;
    float scale = gamma[j] * (1.0f / sqrtf(var + 1e-5f));
    for (int a = l; a < 39; a += 64) W1s[a * HID + j] = W1[a * HID + j] * scale;
    if (l == 0) cvec[j] = -s1 * scale + beta[j];
}

// ---- fused MLP ----
// Spill fix (R2 counters: VGPR=52, WRITE_SIZE=112.5MB == PP*39*4 -> xr[39] went
// to scratch and the kernel was HBM-bound on its own spill traffic):
//   * xk is read directly from the LDS tile (lane stride 39 floats -> bank
//     stride 7, gcd(7,32)=1 -> only free 2-way aliasing), no xr[] array.
//   * __launch_bounds__(256,4) -> 128-VGPR budget so acc[64] stays in regs.
__global__ __launch_bounds__(256, 4) void mlp_kernel(const float* __restrict__ x,
                                                     const float* __restrict__ W1s,
                                                     const float* __restrict__ cvec,
                                                     const float* __restrict__ W2,
                                                     const float* __restrict__ b2,
                                                     float* __restrict__ w,
                                                     float* __restrict__ sumw2) {
    __shared__ float xt[256 * 39];
    __shared__ float red[4];
    const size_t base = (size_t)blockIdx.x * 256;
    {
        const size_t g0 = base * 39;
        const size_t gmax = (size_t)PP * 39;
        for (int idx = threadIdx.x; idx < 256 * 39; idx += 256) {
            size_t g = g0 + idx;
            xt[idx] = (g < gmax) ? x[g] : 0.f;
        }
    }
    __syncthreads();

    const float* __restrict__ xrow = &xt[threadIdx.x * 39];

    float wacc = 0.f;
#pragma unroll 1
    for (int c = 0; c < 2; ++c) {
        float acc[64];
#pragma unroll
        for (int jj = 0; jj < 64; ++jj) acc[jj] = cvec[c * 64 + jj];
#pragma unroll 1
        for (int k = 0; k < 39; ++k) {
            const float xk = xrow[k];
            const float* wrow = &W1s[k * HID + c * 64];
#pragma unroll
            for (int jj = 0; jj < 64; ++jj) acc[jj] = fmaf(xk, wrow[jj], acc[jj]);
        }
#pragma unroll
        for (int jj = 0; jj < 64; ++jj)
            wacc = fmaf(fmaxf(acc[jj], 0.f), W2[c * 64 + jj], wacc);
    }

    const size_t p = base + threadIdx.x;
    const float wv = wacc + b2[0];
    float sq = 0.f;
    if (p < (size_t)PP) { w[p] = wv; sq = wv * wv; }
    sq = wave_reduce_sum(sq);
    if ((threadIdx.x & 63) == 0) red[threadIdx.x >> 6] = sq;
    __syncthreads();
    if (threadIdx.x == 0) atomicAdd(sumw2, red[0] + red[1] + red[2] + red[3]);
}

// ---- W build ----
__global__ __launch_bounds__(256) void buildW(const float* __restrict__ w,
                                              float* __restrict__ W) {
    __shared__ float tile[16][17];
    const int bi = blockIdx.y, bj = blockIdx.x;
    if (bi > bj) return;
    const int ty = threadIdx.x >> 4, tx = threadIdx.x & 15;
    const int i = bi * 16 + ty, j = bj * 16 + tx;
    float v = 0.f;
    if (i < j) {
        int p = i * (NM - 1) - (i * (i - 1)) / 2 + (j - i - 1);
        v = w[p];
    }
    tile[ty][tx] = v;
    __syncthreads();
    if (bi == bj) {
        float out = (i < j) ? v : ((i > j) ? tile[tx][ty] : 0.f);
        W[(size_t)i * NM + j] = out;
    } else {
        W[(size_t)i * NM + j] = v;
        W[(size_t)(bj * 16 + ty) * NM + (bi * 16 + tx)] = tile[tx][ty];
    }
}

// ---- V = V0 / ||row|| ----
__global__ __launch_bounds__(256) void v0norm(const float* __restrict__ V0,
                                              float* __restrict__ V) {
    const int i = blockIdx.x * 4 + (threadIdx.x >> 6);
    const int c = threadIdx.x & 63;
    float v = V0[(size_t)i * RANK + c];
    float s = wave_reduce_sum(v * v);
    V[(size_t)i * RANK + c] = v * (1.0f / sqrtf(s));
}

// ---- one SDP step: Vout = rownorm(Vin + lr * W @ Vin) ----
// 240 blocks x 512 threads (8 waves). Block owns 5 rows; wave = j-chunk of 150;
// lane = rank column. W via wave-uniform scalar loads; V via coalesced 256B loads,
// software-pipelined through 3 named 30-deep register buffers (60-90 in flight).
// lr is computed at kernel entry (uniform scalar load) instead of sitting as a
// dependent load on the post-barrier critical path.
// FMA order per acc[r] is strict t=0..149 -> bitwise-identical numerics.
#define SDP_BLOCKS 240
#define ROWS_PB 5
#define VU 30

__device__ __forceinline__ void sdp_loadv(float* buf, const float* __restrict__ Vb, int tb) {
#pragma unroll
    for (int u = 0; u < VU; ++u) buf[u] = Vb[(size_t)(tb + u) * RANK];
}

__device__ __forceinline__ void sdp_fmav(float* acc, const float* buf,
                                         const float* __restrict__ Wb, int tb) {
#pragma unroll
    for (int u = 0; u < VU; ++u) {
#pragma unroll
        for (int r = 0; r < ROWS_PB; ++r)
            acc[r] = fmaf(Wb[(size_t)r * NM + tb + u], buf[u], acc[r]);
    }
}

__global__ __launch_bounds__(512) void sdp_step(const float* __restrict__ Vin,
                                                float* __restrict__ Vout,
                                                const float* __restrict__ W,
                                                const float* __restrict__ sumw2) {
    __shared__ float part[8][ROWS_PB][64];   // 10 KB
    const int tid = threadIdx.x;
    const int c = tid & 63;
    const int wvid = tid >> 6;                      // 0..7
    const int i0 = blockIdx.x * ROWS_PB;
    const int j0 = __builtin_amdgcn_readfirstlane(wvid * 150);
    const float lr = 1.0f / (sqrtf(2.0f * sumw2[0]) + 1e-8f);

    const float* __restrict__ Wb = W + (size_t)i0 * NM + j0;
    const float* __restrict__ Vb = Vin + (size_t)j0 * RANK + c;

    float acc[ROWS_PB] = {0.f, 0.f, 0.f, 0.f, 0.f};
    float va[VU], vb[VU], vc[VU];

    // pipelined 5 batches of 30: loads lead their consuming FMA group by >=2 batches
    sdp_loadv(va, Vb, 0);
    sdp_loadv(vb, Vb, 30);
    sdp_loadv(vc, Vb, 60);
    sdp_fmav(acc, va, Wb, 0);
    sdp_loadv(va, Vb, 90);          // WAR on va: issues after fmav(va) in program order
    sdp_fmav(acc, vb, Wb, 30);
    sdp_loadv(vb, Vb, 120);
    sdp_fmav(acc, vc, Wb, 60);
    sdp_fmav(acc, va, Wb, 90);
    sdp_fmav(acc, vb, Wb, 120);

#pragma unroll
    for (int r = 0; r < ROWS_PB; ++r) part[wvid][r][c] = acc[r];
    __syncthreads();

    if (tid < ROWS_PB * 64) {
        const int r2 = tid >> 6, c2 = tid & 63;
        float s = 0.f;
#pragma unroll
        for (int k = 0; k < 8; ++k) s += part[k][r2][c2];
        float y = Vin[(size_t)(i0 + r2) * RANK + c2] + lr * s;
        float n = wave_reduce_sum(y * y);
        Vout[(size_t)(i0 + r2) * RANK + c2] = y * (1.0f / sqrtf(n));
    }
}

// ---- out = clip(V V^T, 0, 1): 128x128 symmetric tiles, 8x8 frags ----
__global__ __launch_bounds__(256) void vvt_kernel(const float* __restrict__ V,
                                                  float* __restrict__ out) {
    const int bi = blockIdx.y, bj = blockIdx.x;
    if (bi > bj) return;
    __shared__ __align__(16) float Ti[64][132];   // [k][row]
    __shared__ __align__(16) float Tj[64][132];
    const int tid = threadIdx.x;
    for (int idx = tid; idx < 128 * 64; idx += 256) {
        int row = idx >> 6, k = idx & 63;
        int gi = bi * 128 + row, gj = bj * 128 + row;
        Ti[k][row] = (gi < NM) ? V[(size_t)gi * RANK + k] : 0.f;
        Tj[k][row] = (gj < NM) ? V[(size_t)gj * RANK + k] : 0.f;
    }
    __syncthreads();
    const int ty = tid >> 4, tx = tid & 15;
    float acc[8][8];
#pragma unroll
    for (int a = 0; a < 8; ++a)
#pragma unroll
        for (int b = 0; b < 8; ++b) acc[a][b] = 0.f;
    for (int k = 0; k < 64; ++k) {
        float4 a0 = *(const float4*)&Ti[k][ty * 8];
        float4 a1 = *(const float4*)&Ti[k][ty * 8 + 4];
        float4 b0 = *(const float4*)&Tj[k][tx * 8];
        float4 b1 = *(const float4*)&Tj[k][tx * 8 + 4];
        float av[8] = {a0.x, a0.y, a0.z, a0.w, a1.x, a1.y, a1.z, a1.w};
        float bv[8] = {b0.x, b0.y, b0.z, b0.w, b1.x, b1.y, b1.z, b1.w};
#pragma unroll
        for (int a = 0; a < 8; ++a)
#pragma unroll
            for (int b = 0; b < 8; ++b)
                acc[a][b] = fmaf(av[a], bv[b], acc[a][b]);
    }
#pragma unroll
    for (int a = 0; a < 8; ++a) {
        int i = bi * 128 + 8 * ty + a;
        if (i >= NM) break;
        int jb = bj * 128 + 8 * tx;
        if (jb + 7 < NM) {
            float4 s0 = {fminf(fmaxf(acc[a][0], 0.f), 1.f), fminf(fmaxf(acc[a][1], 0.f), 1.f),
                         fminf(fmaxf(acc[a][2], 0.f), 1.f), fminf(fmaxf(acc[a][3], 0.f), 1.f)};
            float4 s1 = {fminf(fmaxf(acc[a][4], 0.f), 1.f), fminf(fmaxf(acc[a][5], 0.f), 1.f),
                         fminf(fmaxf(acc[a][6], 0.f), 1.f), fminf(fmaxf(acc[a][7], 0.f), 1.f)};
            *(float4*)&out[(size_t)i * NM + jb] = s0;
            *(float4*)&out[(size_t)i * NM + jb + 4] = s1;
        } else {
#pragma unroll
            for (int b = 0; b < 8; ++b) {
                int j = jb + b;
                if (j < NM) out[(size_t)i * NM + j] = fminf(fmaxf(acc[a][b], 0.f), 1.f);
            }
        }
    }
    if (bi != bj) {
#pragma unroll
        for (int b = 0; b < 8; ++b) {
            int j = bj * 128 + 8 * tx + b;
            if (j >= NM) break;
            int ib = bi * 128 + 8 * ty;
            if (ib + 7 < NM) {
                float4 s0 = {fminf(fmaxf(acc[0][b], 0.f), 1.f), fminf(fmaxf(acc[1][b], 0.f), 1.f),
                             fminf(fmaxf(acc[2][b], 0.f), 1.f), fminf(fmaxf(acc[3][b], 0.f), 1.f)};
                float4 s1 = {fminf(fmaxf(acc[4][b], 0.f), 1.f), fminf(fmaxf(acc[5][b], 0.f), 1.f),
                             fminf(fmaxf(acc[6][b], 0.f), 1.f), fminf(fmaxf(acc[7][b], 0.f), 1.f)};
                *(float4*)&out[(size_t)j * NM + ib] = s0;
                *(float4*)&out[(size_t)j * NM + ib + 4] = s1;
            } else {
#pragma unroll
                for (int a = 0; a < 8; ++a) {
                    int i = ib + a;
                    if (i < NM) out[(size_t)j * NM + i] = fminf(fmaxf(acc[a][b], 0.f), 1.f);
                }
            }
        }
    }
}

extern "C" void kernel_launch(void* const* d_in, const int* in_sizes, int n_in,
                              void* d_out, int out_size, void* d_ws, size_t ws_size,
                              hipStream_t stream) {
    const float* x     = (const float*)d_in[0];
    const float* W1    = (const float*)d_in[1];
    const float* gamma = (const float*)d_in[3];
    const float* beta  = (const float*)d_in[4];
    const float* W2    = (const float*)d_in[5];
    const float* b2    = (const float*)d_in[6];
    const float* V0    = (const float*)d_in[7];
    float* out = (float*)d_out;

    float* ws    = (float*)d_ws;
    float* S     = ws + OFF_S;
    float* sumw2 = ws + OFF_SUMW2;
    float* cvec  = ws + OFF_CVEC;
    float* W1s   = ws + OFF_W1S;
    float* wvec  = ws + OFF_WVEC;
    float* Wmat  = ws + OFF_WMAT;
    float* Va    = ws + OFF_VA;
    float* Vb    = ws + OFF_VB;

    zero_kernel<<<7, 256, 0, stream>>>(ws, OFF_W1S);   // S + sumw2
    stats_kernel<<<STATS_BLOCKS, 256, 0, stream>>>(x, S);
    bn_prep<<<HID, 64, 0, stream>>>(S, W1, gamma, beta, W1s, cvec);
    mlp_kernel<<<(PP + 255) / 256, 256, 0, stream>>>(x, W1s, cvec, W2, b2, wvec, sumw2);
    buildW<<<dim3(75, 75), 256, 0, stream>>>(wvec, Wmat);
    v0norm<<<NM / 4, 256, 0, stream>>>(V0, Va);
    for (int it = 0; it < SDP_ITERS; ++it) {
        const float* vin = (it & 1) ? Vb : Va;
        float* vout      = (it & 1) ? Va : Vb;
        sdp_step<<<SDP_BLOCKS, 512, 0, stream>>>(vin, vout, Wmat, sumw2);
    }
    // iter 99 (odd) writes Va
    vvt_kernel<<<dim3(10, 10), 256, 0, stream>>>(Va, out);
}

// Round 4
// 1171.941 us; speedup vs baseline: 2.5341x; 1.0087x over previous
//
#include <hip/hip_runtime.h>

#define NM 1200
#define PP 719400      // NM*(NM-1)/2
#define HID 128
#define RANK 64
#define SDP_ITERS 100

// ---------------- ws layout (floats) ----------------
#define OFF_S      0
#define OFF_SUMW2  1600
#define OFF_CVEC   1664
#define OFF_W1S    1792
#define OFF_WVEC   6912
#define OFF_WMAT   726400
#define OFF_VA     2166400
#define OFF_VB     2243200

__device__ __forceinline__ float wave_reduce_sum(float v) {
#pragma unroll
    for (int o = 32; o > 0; o >>= 1) v += __shfl_xor(v, o, 64);
    return v;
}

__global__ __launch_bounds__(256) void zero_kernel(float* __restrict__ ws, int n) {
    int i = blockIdx.x * 256 + threadIdx.x;
    if (i < n) ws[i] = 0.0f;
}

// ---- pass 1: S[40x40] = [x | 1]^T [x | 1] ----
#define STATS_BLOCKS 1024
#define KT 40                      // k-rows per tile
__global__ __launch_bounds__(256) void stats_kernel(const float* __restrict__ x,
                                                    float* __restrict__ S) {
    __shared__ __align__(16) float tile[2][KT * 48];
    __shared__ float Sacc[48 * 48];
    const int tid = threadIdx.x;
    for (int i = tid; i < 48 * 48; i += 256) Sacc[i] = 0.f;
    // pad columns 40..47 are zero forever (never rewritten)
    for (int i = tid; i < 2 * KT * 8; i += 256) {
        int b = i / (KT * 8);
        int rem = i - b * (KT * 8);
        int r = rem >> 3, k = rem & 7;
        tile[b][r * 48 + 40 + k] = 0.f;
    }

    const int rpb = (PP + STATS_BLOCKS - 1) / STATS_BLOCKS;  // 703
    const int r0 = blockIdx.x * rpb;
    const int r1 = min(r0 + rpb, PP);

    // staging map: 200 threads, thread -> (row sr, col-chunk sc of 8)
    const bool stg = tid < 200;
    const int sr = tid / 5;                 // 0..39 (junk >=200, never used)
    const int sc = (tid - sr * 5) * 8;      // 0,8,16,24,32
    float* const dA = &tile[0][sr * 48 + sc];
    float* const dB = &tile[1][sr * 48 + sc];
    const float* const srcb = x + (size_t)sr * 39 + sc;
    const bool tail = (sc == 32);           // chunk 4: cols 32..38 + bias col 39

    const int z  = tid >> 6;                // wave id 0..3 -> k offset
    const int ln = tid & 63;
    const int ty = ln >> 3, tx = ln & 7;

    float acc[6][6];
#pragma unroll
    for (int a = 0; a < 6; ++a)
#pragma unroll
        for (int b = 0; b < 6; ++b) acc[a][b] = 0.f;

    float v[8];
    {   // prologue: load first tile
        const float* s = srcb + (size_t)r0 * 39;
        const bool ok = stg && (r0 + sr < r1);
#pragma unroll
        for (int k = 0; k < 8; ++k) v[k] = 0.f;
        if (ok) {
#pragma unroll
            for (int k = 0; k < 7; ++k) v[k] = s[k];
            v[7] = tail ? 1.0f : s[7];
        }
    }
    if (stg) {
        *(float4*)dA       = make_float4(v[0], v[1], v[2], v[3]);
        *(float4*)(dA + 4) = make_float4(v[4], v[5], v[6], v[7]);
    }
    __syncthreads();

    int cur = 0;
    for (int t = r0; t < r1; t += KT) {
        const int tn = t + KT;
        const bool more = tn < r1;          // uniform across block
        float vn[8];
        if (more) {                         // issue next tile's loads now
            const float* s = srcb + (size_t)tn * 39;
            const bool ok = stg && (tn + sr < r1);
#pragma unroll
            for (int k = 0; k < 8; ++k) vn[k] = 0.f;
            if (ok) {
#pragma unroll
                for (int k = 0; k < 7; ++k) vn[k] = s[k];
                vn[7] = tail ? 1.0f : s[7];
            }
        }
        // compute current tile (hides the loads above)
        const float* tb = tile[cur];
#pragma unroll 2
        for (int kk = 0; kk < KT / 4; ++kk) {
            const float* row = &tb[(kk * 4 + z) * 48];
            float2 a0 = *(const float2*)(row + ty * 6);
            float2 a1 = *(const float2*)(row + ty * 6 + 2);
            float2 a2 = *(const float2*)(row + ty * 6 + 4);
            float2 b0 = *(const float2*)(row + tx * 6);
            float2 b1 = *(const float2*)(row + tx * 6 + 2);
            float2 b2 = *(const float2*)(row + tx * 6 + 4);
            float av[6] = {a0.x, a0.y, a1.x, a1.y, a2.x, a2.y};
            float bv[6] = {b0.x, b0.y, b1.x, b1.y, b2.x, b2.y};
#pragma unroll
            for (int a = 0; a < 6; ++a)
#pragma unroll
                for (int b = 0; b < 6; ++b)
                    acc[a][b] = fmaf(av[a], bv[b], acc[a][b]);
        }
        if (more && stg) {                  // write next tile into the other buffer
            float* d = cur ? dA : dB;
            *(float4*)d       = make_float4(vn[0], vn[1], vn[2], vn[3]);
            *(float4*)(d + 4) = make_float4(vn[4], vn[5], vn[6], vn[7]);
        }
        __syncthreads();
        cur ^= 1;
    }

#pragma unroll
    for (int a = 0; a < 6; ++a)
#pragma unroll
        for (int b = 0; b < 6; ++b)
            atomicAdd(&Sacc[(ty * 6 + a) * 48 + tx * 6 + b], acc[a][b]);
    __syncthreads();
    for (int i = tid; i < 1600; i += 256) {
        int r = i / 40, c = i - r * 40;
        atomicAdd(&S[i], Sacc[r * 48 + c]);
    }
}

// ---- BN folding ----
__global__ __launch_bounds__(64) void bn_prep(const float* __restrict__ S,
                                              const float* __restrict__ W1,
                                              const float* __restrict__ gamma,
                                              const float* __restrict__ beta,
                                              float* __restrict__ W1s,
                                              float* __restrict__ cvec) {
    const int j = blockIdx.x;
    const int l = threadIdx.x;
    const float invP = 1.0f / (float)PP;
    float q = 0.f;
    for (int idx = l; idx < 39 * 39; idx += 64) {
        int a = idx / 39, b = idx - a * 39;
        q = fmaf(S[a * 40 + b], W1[a * HID + j] * W1[b * HID + j], q);
    }
    float s1 = (l < 39) ? (S[39 * 40 + l] * invP) * W1[l * HID + j] : 0.f;
    q = wave_reduce_sum(q);
    s1 = wave_reduce_sum(s1);
    float var = q * invP - s1 * s1;
    float scale = gamma[j] * (1.0f / sqrtf(var + 1e-5f));
    for (int a = l; a < 39; a += 64) W1s[a * HID + j] = W1[a * HID + j] * scale;
    if (l == 0) cvec[j] = -s1 * scale + beta[j];
}

// ---- fused MLP ----
// R3 counters: VGPR=52 with acc[64] -> compiler loop-interchanged (slow).
// Fix: strips of 32 (acc[32] fits ANY register budget -> no reason to
// interchange). Per k: one LDS read (lane stride 39 -> free 2-way) + 32 FMAs
// with wave-uniform (scalar-cached) W1s operands. Summation order per output
// unchanged (jj ascending 0..127, k ascending) -> bitwise identical.
__global__ __launch_bounds__(256, 4) void mlp_kernel(const float* __restrict__ x,
                                                     const float* __restrict__ W1s,
                                                     const float* __restrict__ cvec,
                                                     const float* __restrict__ W2,
                                                     const float* __restrict__ b2,
                                                     float* __restrict__ w,
                                                     float* __restrict__ sumw2) {
    __shared__ float xt[256 * 39];
    __shared__ float red[4];
    const size_t base = (size_t)blockIdx.x * 256;
    {
        const size_t g0 = base * 39;
        const size_t gmax = (size_t)PP * 39;
        for (int idx = threadIdx.x; idx < 256 * 39; idx += 256) {
            size_t g = g0 + idx;
            xt[idx] = (g < gmax) ? x[g] : 0.f;
        }
    }
    __syncthreads();

    const float* __restrict__ xrow = &xt[threadIdx.x * 39];

    float wacc = 0.f;
#pragma unroll 1
    for (int s = 0; s < 4; ++s) {
        float acc[32];
#pragma unroll
        for (int jj = 0; jj < 32; ++jj) acc[jj] = cvec[s * 32 + jj];
#pragma unroll 1
        for (int k = 0; k < 39; ++k) {
            const float xk = xrow[k];
            const float* wrow = &W1s[k * HID + s * 32];
#pragma unroll
            for (int jj = 0; jj < 32; ++jj) acc[jj] = fmaf(xk, wrow[jj], acc[jj]);
        }
#pragma unroll
        for (int jj = 0; jj < 32; ++jj)
            wacc = fmaf(fmaxf(acc[jj], 0.f), W2[s * 32 + jj], wacc);
    }

    const size_t p = base + threadIdx.x;
    const float wv = wacc + b2[0];
    float sq = 0.f;
    if (p < (size_t)PP) { w[p] = wv; sq = wv * wv; }
    sq = wave_reduce_sum(sq);
    if ((threadIdx.x & 63) == 0) red[threadIdx.x >> 6] = sq;
    __syncthreads();
    if (threadIdx.x == 0) atomicAdd(sumw2, red[0] + red[1] + red[2] + red[3]);
}

// ---- W build ----
__global__ __launch_bounds__(256) void buildW(const float* __restrict__ w,
                                              float* __restrict__ W) {
    __shared__ float tile[16][17];
    const int bi = blockIdx.y, bj = blockIdx.x;
    if (bi > bj) return;
    const int ty = threadIdx.x >> 4, tx = threadIdx.x & 15;
    const int i = bi * 16 + ty, j = bj * 16 + tx;
    float v = 0.f;
    if (i < j) {
        int p = i * (NM - 1) - (i * (i - 1)) / 2 + (j - i - 1);
        v = w[p];
    }
    tile[ty][tx] = v;
    __syncthreads();
    if (bi == bj) {
        float out = (i < j) ? v : ((i > j) ? tile[tx][ty] : 0.f);
        W[(size_t)i * NM + j] = out;
    } else {
        W[(size_t)i * NM + j] = v;
        W[(size_t)(bj * 16 + ty) * NM + (bi * 16 + tx)] = tile[tx][ty];
    }
}

// ---- V = V0 / ||row|| ----
__global__ __launch_bounds__(256) void v0norm(const float* __restrict__ V0,
                                              float* __restrict__ V) {
    const int i = blockIdx.x * 4 + (threadIdx.x >> 6);
    const int c = threadIdx.x & 63;
    float v = V0[(size_t)i * RANK + c];
    float s = wave_reduce_sum(v * v);
    V[(size_t)i * RANK + c] = v * (1.0f / sqrtf(s));
}

// ---- one SDP step: Vout = rownorm(Vin + lr * W @ Vin) ----
// 240 blocks x 512 threads (8 waves). Block owns 5 rows; wave = j-chunk of 150;
// lane = rank column.
// R4 change: W operands moved OFF the scalar pipe. The wave-uniform s_load
// path serialized into ~10 lgkmcnt round-trips per iteration (L3-cold each
// dispatch). Now W comes via per-lane float2 vector loads at a wave-uniform
// address (HW broadcasts one line; 8-B alignment provable: j0*4 = 600*wvid),
// double-buffered in 8-wide batches alongside the V stream -> everything sits
// in the 64-deep vmcnt queue with a 2-batch prefetch distance.
// FMA order per acc[r] is strict t ascending -> bitwise-identical numerics.
#define SDP_BLOCKS 240
#define ROWS_PB 5

__device__ __forceinline__ void ld_w8(float2 (*wb)[4], const float* __restrict__ Wb, int t0) {
#pragma unroll
    for (int r = 0; r < ROWS_PB; ++r) {
#pragma unroll
        for (int h = 0; h < 4; ++h)
            wb[r][h] = *(const float2*)(Wb + (size_t)r * NM + t0 + 2 * h);
    }
}
__device__ __forceinline__ void ld_v8(float* v, const float* __restrict__ Vb, int t0) {
#pragma unroll
    for (int u = 0; u < 8; ++u) v[u] = Vb[(size_t)(t0 + u) * RANK];
}
__device__ __forceinline__ void fma8(float* acc, const float2 (*wb)[4], const float* v) {
#pragma unroll
    for (int u = 0; u < 8; ++u) {
#pragma unroll
        for (int r = 0; r < ROWS_PB; ++r) {
            const float wv = (u & 1) ? wb[r][u >> 1].y : wb[r][u >> 1].x;
            acc[r] = fmaf(wv, v[u], acc[r]);
        }
    }
}

__global__ __launch_bounds__(512) void sdp_step(const float* __restrict__ Vin,
                                                float* __restrict__ Vout,
                                                const float* __restrict__ W,
                                                const float* __restrict__ sumw2) {
    __shared__ float part[8][ROWS_PB][64];   // 10 KB
    const int tid = threadIdx.x;
    const int c = tid & 63;
    const int wvid = tid >> 6;                      // 0..7
    const int i0 = blockIdx.x * ROWS_PB;
    const int j0 = __builtin_amdgcn_readfirstlane(wvid * 150);
    const float lr = 1.0f / (sqrtf(2.0f * sumw2[0]) + 1e-8f);

    const float* __restrict__ Wb = W + (size_t)i0 * NM + j0;
    const float* __restrict__ Vb = Vin + (size_t)j0 * RANK + c;

    float acc[ROWS_PB] = {0.f, 0.f, 0.f, 0.f, 0.f};

    // 18 batches of 8 over t in [0,144) + tail of 6; j-partition identical to R3.
    float2 wA[ROWS_PB][4], wB[ROWS_PB][4];
    float  vA[8], vB[8];
    float2 wT[ROWS_PB][3];
    float  vT[6];

    ld_w8(wA, Wb, 0);   ld_v8(vA, Vb, 0);
    ld_w8(wB, Wb, 8);   ld_v8(vB, Vb, 8);

#pragma unroll
    for (int k = 0; k < 9; ++k) {          // consume batches 2k, 2k+1
        fma8(acc, wA, vA);
        if (2 * k + 2 < 18) { ld_w8(wA, Wb, 16 * k + 16); ld_v8(vA, Vb, 16 * k + 16); }
        fma8(acc, wB, vB);
        if (2 * k + 3 < 18) { ld_w8(wB, Wb, 16 * k + 24); ld_v8(vB, Vb, 16 * k + 24); }
        if (k == 7) {                      // issue tail loads (t=144..149)
#pragma unroll
            for (int r = 0; r < ROWS_PB; ++r)
#pragma unroll
                for (int h = 0; h < 3; ++h)
                    wT[r][h] = *(const float2*)(Wb + (size_t)r * NM + 144 + 2 * h);
#pragma unroll
            for (int u = 0; u < 6; ++u) vT[u] = Vb[(size_t)(144 + u) * RANK];
        }
    }
    // tail FMAs: t = 144..149
#pragma unroll
    for (int u = 0; u < 6; ++u) {
#pragma unroll
        for (int r = 0; r < ROWS_PB; ++r) {
            const float wv = (u & 1) ? wT[r][u >> 1].y : wT[r][u >> 1].x;
            acc[r] = fmaf(wv, vT[u], acc[r]);
        }
    }

#pragma unroll
    for (int r = 0; r < ROWS_PB; ++r) part[wvid][r][c] = acc[r];
    __syncthreads();

    if (tid < ROWS_PB * 64) {
        const int r2 = tid >> 6, c2 = tid & 63;
        float s = 0.f;
#pragma unroll
        for (int k = 0; k < 8; ++k) s += part[k][r2][c2];
        float y = Vin[(size_t)(i0 + r2) * RANK + c2] + lr * s;
        float n = wave_reduce_sum(y * y);
        Vout[(size_t)(i0 + r2) * RANK + c2] = y * (1.0f / sqrtf(n));
    }
}

// ---- out = clip(V V^T, 0, 1): 128x128 symmetric tiles, 8x8 frags ----
__global__ __launch_bounds__(256) void vvt_kernel(const float* __restrict__ V,
                                                  float* __restrict__ out) {
    const int bi = blockIdx.y, bj = blockIdx.x;
    if (bi > bj) return;
    __shared__ __align__(16) float Ti[64][132];   // [k][row]
    __shared__ __align__(16) float Tj[64][132];
    const int tid = threadIdx.x;
    for (int idx = tid; idx < 128 * 64; idx += 256) {
        int row = idx >> 6, k = idx & 63;
        int gi = bi * 128 + row, gj = bj * 128 + row;
        Ti[k][row] = (gi < NM) ? V[(size_t)gi * RANK + k] : 0.f;
        Tj[k][row] = (gj < NM) ? V[(size_t)gj * RANK + k] : 0.f;
    }
    __syncthreads();
    const int ty = tid >> 4, tx = tid & 15;
    float acc[8][8];
#pragma unroll
    for (int a = 0; a < 8; ++a)
#pragma unroll
        for (int b = 0; b < 8; ++b) acc[a][b] = 0.f;
    for (int k = 0; k < 64; ++k) {
        float4 a0 = *(const float4*)&Ti[k][ty * 8];
        float4 a1 = *(const float4*)&Ti[k][ty * 8 + 4];
        float4 b0 = *(const float4*)&Tj[k][tx * 8];
        float4 b1 = *(const float4*)&Tj[k][tx * 8 + 4];
        float av[8] = {a0.x, a0.y, a0.z, a0.w, a1.x, a1.y, a1.z, a1.w};
        float bv[8] = {b0.x, b0.y, b0.z, b0.w, b1.x, b1.y, b1.z, b1.w};
#pragma unroll
        for (int a = 0; a < 8; ++a)
#pragma unroll
            for (int b = 0; b < 8; ++b)
                acc[a][b] = fmaf(av[a], bv[b], acc[a][b]);
    }
#pragma unroll
    for (int a = 0; a < 8; ++a) {
        int i = bi * 128 + 8 * ty + a;
        if (i >= NM) break;
        int jb = bj * 128 + 8 * tx;
        if (jb + 7 < NM) {
            float4 s0 = {fminf(fmaxf(acc[a][0], 0.f), 1.f), fminf(fmaxf(acc[a][1], 0.f), 1.f),
                         fminf(fmaxf(acc[a][2], 0.f), 1.f), fminf(fmaxf(acc[a][3], 0.f), 1.f)};
            float4 s1 = {fminf(fmaxf(acc[a][4], 0.f), 1.f), fminf(fmaxf(acc[a][5], 0.f), 1.f),
                         fminf(fmaxf(acc[a][6], 0.f), 1.f), fminf(fmaxf(acc[a][7], 0.f), 1.f)};
            *(float4*)&out[(size_t)i * NM + jb] = s0;
            *(float4*)&out[(size_t)i * NM + jb + 4] = s1;
        } else {
#pragma unroll
            for (int b = 0; b < 8; ++b) {
                int j = jb + b;
                if (j < NM) out[(size_t)i * NM + j] = fminf(fmaxf(acc[a][b], 0.f), 1.f);
            }
        }
    }
    if (bi != bj) {
#pragma unroll
        for (int b = 0; b < 8; ++b) {
            int j = bj * 128 + 8 * tx + b;
            if (j >= NM) break;
            int ib = bi * 128 + 8 * ty;
            if (ib + 7 < NM) {
                float4 s0 = {fminf(fmaxf(acc[0][b], 0.f), 1.f), fminf(fmaxf(acc[1][b], 0.f), 1.f),
                             fminf(fmaxf(acc[2][b], 0.f), 1.f), fminf(fmaxf(acc[3][b], 0.f), 1.f)};
                float4 s1 = {fminf(fmaxf(acc[4][b], 0.f), 1.f), fminf(fmaxf(acc[5][b], 0.f), 1.f),
                             fminf(fmaxf(acc[6][b], 0.f), 1.f), fminf(fmaxf(acc[7][b], 0.f), 1.f)};
                *(float4*)&out[(size_t)j * NM + ib] = s0;
                *(float4*)&out[(size_t)j * NM + ib + 4] = s1;
            } else {
#pragma unroll
                for (int a = 0; a < 8; ++a) {
                    int i = ib + a;
                    if (i < NM) out[(size_t)j * NM + i] = fminf(fmaxf(acc[a][b], 0.f), 1.f);
                }
            }
        }
    }
}

extern "C" void kernel_launch(void* const* d_in, const int* in_sizes, int n_in,
                              void* d_out, int out_size, void* d_ws, size_t ws_size,
                              hipStream_t stream) {
    const float* x     = (const float*)d_in[0];
    const float* W1    = (const float*)d_in[1];
    const float* gamma = (const float*)d_in[3];
    const float* beta  = (const float*)d_in[4];
    const float* W2    = (const float*)d_in[5];
    const float* b2    = (const float*)d_in[6];
    const float* V0    = (const float*)d_in[7];
    float* out = (float*)d_out;

    float* ws    = (float*)d_ws;
    float* S     = ws + OFF_S;
    float* sumw2 = ws + OFF_SUMW2;
    float* cvec  = ws + OFF_CVEC;
    float* W1s   = ws + OFF_W1S;
    float* wvec  = ws + OFF_WVEC;
    float* Wmat  = ws + OFF_WMAT;
    float* Va    = ws + OFF_VA;
    float* Vb    = ws + OFF_VB;

    zero_kernel<<<7, 256, 0, stream>>>(ws, OFF_W1S);   // S + sumw2
    stats_kernel<<<STATS_BLOCKS, 256, 0, stream>>>(x, S);
    bn_prep<<<HID, 64, 0, stream>>>(S, W1, gamma, beta, W1s, cvec);
    mlp_kernel<<<(PP + 255) / 256, 256, 0, stream>>>(x, W1s, cvec, W2, b2, wvec, sumw2);
    buildW<<<dim3(75, 75), 256, 0, stream>>>(wvec, Wmat);
    v0norm<<<NM / 4, 256, 0, stream>>>(V0, Va);
    for (int it = 0; it < SDP_ITERS; ++it) {
        const float* vin = (it & 1) ? Vb : Va;
        float* vout      = (it & 1) ? Va : Vb;
        sdp_step<<<SDP_BLOCKS, 512, 0, stream>>>(vin, vout, Wmat, sumw2);
    }
    // iter 99 (odd) writes Va
    vvt_kernel<<<dim3(10, 10), 256, 0, stream>>>(Va, out);
}

// Round 5
// 1149.069 us; speedup vs baseline: 2.5846x; 1.0199x over previous
//
#include <hip/hip_runtime.h>

#define NM 1200
#define PP 719400      // NM*(NM-1)/2
#define HID 128
#define RANK 64
#define SDP_ITERS 100

// ---------------- ws layout (floats) ----------------
#define OFF_S      0
#define OFF_SUMW2  1600
#define OFF_CVEC   1664
#define OFF_W1S    1792
#define OFF_WVEC   6912
#define OFF_WMAT   726400
#define OFF_VA     2166400
#define OFF_VB     2243200

__device__ __forceinline__ float wave_reduce_sum(float v) {
#pragma unroll
    for (int o = 32; o > 0; o >>= 1) v += __shfl_xor(v, o, 64);
    return v;
}

__global__ __launch_bounds__(256) void zero_kernel(float* __restrict__ ws, int n) {
    int i = blockIdx.x * 256 + threadIdx.x;
    if (i < n) ws[i] = 0.0f;
}

// ---- pass 1: S[40x40] = [x | 1]^T [x | 1] ----
#define STATS_BLOCKS 1024
#define KT 40                      // k-rows per tile
__global__ __launch_bounds__(256) void stats_kernel(const float* __restrict__ x,
                                                    float* __restrict__ S) {
    __shared__ __align__(16) float tile[2][KT * 48];
    __shared__ float Sacc[48 * 48];
    const int tid = threadIdx.x;
    for (int i = tid; i < 48 * 48; i += 256) Sacc[i] = 0.f;
    // pad columns 40..47 are zero forever (never rewritten)
    for (int i = tid; i < 2 * KT * 8; i += 256) {
        int b = i / (KT * 8);
        int rem = i - b * (KT * 8);
        int r = rem >> 3, k = rem & 7;
        tile[b][r * 48 + 40 + k] = 0.f;
    }

    const int rpb = (PP + STATS_BLOCKS - 1) / STATS_BLOCKS;  // 703
    const int r0 = blockIdx.x * rpb;
    const int r1 = min(r0 + rpb, PP);

    // staging map: 200 threads, thread -> (row sr, col-chunk sc of 8)
    const bool stg = tid < 200;
    const int sr = tid / 5;                 // 0..39 (junk >=200, never used)
    const int sc = (tid - sr * 5) * 8;      // 0,8,16,24,32
    float* const dA = &tile[0][sr * 48 + sc];
    float* const dB = &tile[1][sr * 48 + sc];
    const float* const srcb = x + (size_t)sr * 39 + sc;
    const bool tail = (sc == 32);           // chunk 4: cols 32..38 + bias col 39

    const int z  = tid >> 6;                // wave id 0..3 -> k offset
    const int ln = tid & 63;
    const int ty = ln >> 3, tx = ln & 7;

    float acc[6][6];
#pragma unroll
    for (int a = 0; a < 6; ++a)
#pragma unroll
        for (int b = 0; b < 6; ++b) acc[a][b] = 0.f;

    float v[8];
    {   // prologue: load first tile
        const float* s = srcb + (size_t)r0 * 39;
        const bool ok = stg && (r0 + sr < r1);
#pragma unroll
        for (int k = 0; k < 8; ++k) v[k] = 0.f;
        if (ok) {
#pragma unroll
            for (int k = 0; k < 7; ++k) v[k] = s[k];
            v[7] = tail ? 1.0f : s[7];
        }
    }
    if (stg) {
        *(float4*)dA       = make_float4(v[0], v[1], v[2], v[3]);
        *(float4*)(dA + 4) = make_float4(v[4], v[5], v[6], v[7]);
    }
    __syncthreads();

    int cur = 0;
    for (int t = r0; t < r1; t += KT) {
        const int tn = t + KT;
        const bool more = tn < r1;          // uniform across block
        float vn[8];
        if (more) {                         // issue next tile's loads now
            const float* s = srcb + (size_t)tn * 39;
            const bool ok = stg && (tn + sr < r1);
#pragma unroll
            for (int k = 0; k < 8; ++k) vn[k] = 0.f;
            if (ok) {
#pragma unroll
                for (int k = 0; k < 7; ++k) vn[k] = s[k];
                vn[7] = tail ? 1.0f : s[7];
            }
        }
        // compute current tile (hides the loads above)
        const float* tb = tile[cur];
#pragma unroll 2
        for (int kk = 0; kk < KT / 4; ++kk) {
            const float* row = &tb[(kk * 4 + z) * 48];
            float2 a0 = *(const float2*)(row + ty * 6);
            float2 a1 = *(const float2*)(row + ty * 6 + 2);
            float2 a2 = *(const float2*)(row + ty * 6 + 4);
            float2 b0 = *(const float2*)(row + tx * 6);
            float2 b1 = *(const float2*)(row + tx * 6 + 2);
            float2 b2 = *(const float2*)(row + tx * 6 + 4);
            float av[6] = {a0.x, a0.y, a1.x, a1.y, a2.x, a2.y};
            float bv[6] = {b0.x, b0.y, b1.x, b1.y, b2.x, b2.y};
#pragma unroll
            for (int a = 0; a < 6; ++a)
#pragma unroll
                for (int b = 0; b < 6; ++b)
                    acc[a][b] = fmaf(av[a], bv[b], acc[a][b]);
        }
        if (more && stg) {                  // write next tile into the other buffer
            float* d = cur ? dA : dB;
            *(float4*)d       = make_float4(vn[0], vn[1], vn[2], vn[3]);
            *(float4*)(d + 4) = make_float4(vn[4], vn[5], vn[6], vn[7]);
        }
        __syncthreads();
        cur ^= 1;
    }

#pragma unroll
    for (int a = 0; a < 6; ++a)
#pragma unroll
        for (int b = 0; b < 6; ++b)
            atomicAdd(&Sacc[(ty * 6 + a) * 48 + tx * 6 + b], acc[a][b]);
    __syncthreads();
    for (int i = tid; i < 1600; i += 256) {
        int r = i / 40, c = i - r * 40;
        atomicAdd(&S[i], Sacc[r * 48 + c]);
    }
}

// ---- BN folding ----
__global__ __launch_bounds__(64) void bn_prep(const float* __restrict__ S,
                                              const float* __restrict__ W1,
                                              const float* __restrict__ gamma,
                                              const float* __restrict__ beta,
                                              float* __restrict__ W1s,
                                              float* __restrict__ cvec) {
    const int j = blockIdx.x;
    const int l = threadIdx.x;
    const float invP = 1.0f / (float)PP;
    float q = 0.f;
    for (int idx = l; idx < 39 * 39; idx += 64) {
        int a = idx / 39, b = idx - a * 39;
        q = fmaf(S[a * 40 + b], W1[a * HID + j] * W1[b * HID + j], q);
    }
    float s1 = (l < 39) ? (S[39 * 40 + l] * invP) * W1[l * HID + j] : 0.f;
    q = wave_reduce_sum(q);
    s1 = wave_reduce_sum(s1);
    float var = q * invP - s1 * s1;
    float scale = gamma[j] * (1.0f / sqrtf(var + 1e-5f));
    for (int a = l; a < 39; a += 64) W1s[a * HID + j] = W1[a * HID + j] * scale;
    if (l == 0) cvec[j] = -s1 * scale + beta[j];
}

// ---- fused MLP ----
// R4 lesson: the per-k ds_read of xk shared lgkmcnt with the W1s s_loads and
// serialized both (166us). R2 lesson: PARTIAL unroll left xr[k] runtime-indexed
// -> scratch spill (rule: runtime-indexed arrays go to local memory).
// Fix: xr[39] in VGPRs with FULL k-unroll (all indices static), strips of 32
// (R4 proved acc[32] stays in registers). Hot loop = s_load (scalar pipe,
// pipelined) + v_fmac with SGPR operand only. Summation order unchanged
// (jj ascending 0..127 via 4 strips, k ascending) -> bitwise identical.
__global__ __launch_bounds__(256, 4) void mlp_kernel(const float* __restrict__ x,
                                                     const float* __restrict__ W1s,
                                                     const float* __restrict__ cvec,
                                                     const float* __restrict__ W2,
                                                     const float* __restrict__ b2,
                                                     float* __restrict__ w,
                                                     float* __restrict__ sumw2) {
    __shared__ float xt[256 * 39];
    __shared__ float red[4];
    const size_t base = (size_t)blockIdx.x * 256;
    {
        const size_t g0 = base * 39;
        const size_t gmax = (size_t)PP * 39;
        for (int idx = threadIdx.x; idx < 256 * 39; idx += 256) {
            size_t g = g0 + idx;
            xt[idx] = (g < gmax) ? x[g] : 0.f;
        }
    }
    __syncthreads();

    float xr[39];
    {
        const float* __restrict__ xrow = &xt[threadIdx.x * 39];
#pragma unroll
        for (int k = 0; k < 39; ++k) xr[k] = xrow[k];   // full unroll: static idx
    }

    float wacc = 0.f;
#pragma unroll 1
    for (int s = 0; s < 4; ++s) {
        float acc[32];
#pragma unroll
        for (int jj = 0; jj < 32; ++jj) acc[jj] = cvec[s * 32 + jj];
#pragma unroll
        for (int k = 0; k < 39; ++k) {      // FULL unroll: xr[k] static, no DS
            const float xk = xr[k];
            const float* __restrict__ wrow = &W1s[k * HID + s * 32];
#pragma unroll
            for (int jj = 0; jj < 32; ++jj) acc[jj] = fmaf(xk, wrow[jj], acc[jj]);
        }
#pragma unroll
        for (int jj = 0; jj < 32; ++jj)
            wacc = fmaf(fmaxf(acc[jj], 0.f), W2[s * 32 + jj], wacc);
    }

    const size_t p = base + threadIdx.x;
    const float wv = wacc + b2[0];
    float sq = 0.f;
    if (p < (size_t)PP) { w[p] = wv; sq = wv * wv; }
    sq = wave_reduce_sum(sq);
    if ((threadIdx.x & 63) == 0) red[threadIdx.x >> 6] = sq;
    __syncthreads();
    if (threadIdx.x == 0) atomicAdd(sumw2, red[0] + red[1] + red[2] + red[3]);
}

// ---- W build ----
__global__ __launch_bounds__(256) void buildW(const float* __restrict__ w,
                                              float* __restrict__ W) {
    __shared__ float tile[16][17];
    const int bi = blockIdx.y, bj = blockIdx.x;
    if (bi > bj) return;
    const int ty = threadIdx.x >> 4, tx = threadIdx.x & 15;
    const int i = bi * 16 + ty, j = bj * 16 + tx;
    float v = 0.f;
    if (i < j) {
        int p = i * (NM - 1) - (i * (i - 1)) / 2 + (j - i - 1);
        v = w[p];
    }
    tile[ty][tx] = v;
    __syncthreads();
    if (bi == bj) {
        float out = (i < j) ? v : ((i > j) ? tile[tx][ty] : 0.f);
        W[(size_t)i * NM + j] = out;
    } else {
        W[(size_t)i * NM + j] = v;
        W[(size_t)(bj * 16 + ty) * NM + (bi * 16 + tx)] = tile[tx][ty];
    }
}

// ---- V = V0 / ||row|| ----
__global__ __launch_bounds__(256) void v0norm(const float* __restrict__ V0,
                                              float* __restrict__ V) {
    const int i = blockIdx.x * 4 + (threadIdx.x >> 6);
    const int c = threadIdx.x & 63;
    float v = V0[(size_t)i * RANK + c];
    float s = wave_reduce_sum(v * v);
    V[(size_t)i * RANK + c] = v * (1.0f / sqrtf(s));
}

// ---- one SDP step: Vout = rownorm(Vin + lr * W @ Vin) ----
// R5: occupancy attack. 240 blocks x 960 threads (15 waves ~ 3.75 waves/SIMD,
// was 2). Block owns 5 rows; wave = j-chunk of 80 (15 x 80 = 1200); lane =
// rank column. V stream double-buffered 16 deep (VMEM, 2 batches in flight);
// W wave-uniform plain-indexed -> scalar pipe. Per-wave: 400 FMA, 80 V loads,
// 400 W scalar values.
// NOTE: partial-sum grouping changed (15x80 vs 8x150) -> fp association
// differs from prior rounds; output saturates under clip so absmax expected ~0.
#define SDP_BLOCKS 240
#define ROWS_PB 5
#define SDP_WAVES 15
#define JCHUNK 80

__device__ __forceinline__ void sdp_ld16(float* v, const float* __restrict__ Vb, int t0) {
#pragma unroll
    for (int u = 0; u < 16; ++u) v[u] = Vb[(size_t)(t0 + u) * RANK];
}
__device__ __forceinline__ void sdp_fma16(float* acc, const float* v,
                                          const float* __restrict__ Wb, int t0) {
#pragma unroll
    for (int u = 0; u < 16; ++u) {
#pragma unroll
        for (int r = 0; r < ROWS_PB; ++r)
            acc[r] = fmaf(Wb[(size_t)r * NM + t0 + u], v[u], acc[r]);
    }
}

__global__ __launch_bounds__(960) void sdp_step(const float* __restrict__ Vin,
                                                float* __restrict__ Vout,
                                                const float* __restrict__ W,
                                                const float* __restrict__ sumw2) {
    __shared__ float part[SDP_WAVES][ROWS_PB][64];   // 18.75 KB
    const int tid = threadIdx.x;
    const int c = tid & 63;
    const int wvid = tid >> 6;                      // 0..14
    const int i0 = blockIdx.x * ROWS_PB;
    const int j0 = __builtin_amdgcn_readfirstlane(wvid * JCHUNK);
    const float lr = 1.0f / (sqrtf(2.0f * sumw2[0]) + 1e-8f);

    const float* __restrict__ Wb = W + (size_t)i0 * NM + j0;
    const float* __restrict__ Vb = Vin + (size_t)j0 * RANK + c;

    float acc[ROWS_PB] = {0.f, 0.f, 0.f, 0.f, 0.f};
    float va[16], vb[16];

    // 5 batches of 16; V loads lead their consuming FMA group by 2 batches.
    sdp_ld16(va, Vb, 0);
    sdp_ld16(vb, Vb, 16);
    sdp_fma16(acc, va, Wb, 0);
    sdp_ld16(va, Vb, 32);
    sdp_fma16(acc, vb, Wb, 16);
    sdp_ld16(vb, Vb, 48);
    sdp_fma16(acc, va, Wb, 32);
    sdp_ld16(va, Vb, 64);
    sdp_fma16(acc, vb, Wb, 48);
    sdp_fma16(acc, va, Wb, 64);

#pragma unroll
    for (int r = 0; r < ROWS_PB; ++r) part[wvid][r][c] = acc[r];
    __syncthreads();

    if (tid < ROWS_PB * 64) {
        const int r2 = tid >> 6, c2 = tid & 63;
        float s = 0.f;
#pragma unroll
        for (int k = 0; k < SDP_WAVES; ++k) s += part[k][r2][c2];
        float y = Vin[(size_t)(i0 + r2) * RANK + c2] + lr * s;
        float n = wave_reduce_sum(y * y);
        Vout[(size_t)(i0 + r2) * RANK + c2] = y * (1.0f / sqrtf(n));
    }
}

// ---- out = clip(V V^T, 0, 1): 128x128 symmetric tiles, 8x8 frags ----
__global__ __launch_bounds__(256) void vvt_kernel(const float* __restrict__ V,
                                                  float* __restrict__ out) {
    const int bi = blockIdx.y, bj = blockIdx.x;
    if (bi > bj) return;
    __shared__ __align__(16) float Ti[64][132];   // [k][row]
    __shared__ __align__(16) float Tj[64][132];
    const int tid = threadIdx.x;
    for (int idx = tid; idx < 128 * 64; idx += 256) {
        int row = idx >> 6, k = idx & 63;
        int gi = bi * 128 + row, gj = bj * 128 + row;
        Ti[k][row] = (gi < NM) ? V[(size_t)gi * RANK + k] : 0.f;
        Tj[k][row] = (gj < NM) ? V[(size_t)gj * RANK + k] : 0.f;
    }
    __syncthreads();
    const int ty = tid >> 4, tx = tid & 15;
    float acc[8][8];
#pragma unroll
    for (int a = 0; a < 8; ++a)
#pragma unroll
        for (int b = 0; b < 8; ++b) acc[a][b] = 0.f;
    for (int k = 0; k < 64; ++k) {
        float4 a0 = *(const float4*)&Ti[k][ty * 8];
        float4 a1 = *(const float4*)&Ti[k][ty * 8 + 4];
        float4 b0 = *(const float4*)&Tj[k][tx * 8];
        float4 b1 = *(const float4*)&Tj[k][tx * 8 + 4];
        float av[8] = {a0.x, a0.y, a0.z, a0.w, a1.x, a1.y, a1.z, a1.w};
        float bv[8] = {b0.x, b0.y, b0.z, b0.w, b1.x, b1.y, b1.z, b1.w};
#pragma unroll
        for (int a = 0; a < 8; ++a)
#pragma unroll
            for (int b = 0; b < 8; ++b)
                acc[a][b] = fmaf(av[a], bv[b], acc[a][b]);
    }
#pragma unroll
    for (int a = 0; a < 8; ++a) {
        int i = bi * 128 + 8 * ty + a;
        if (i >= NM) break;
        int jb = bj * 128 + 8 * tx;
        if (jb + 7 < NM) {
            float4 s0 = {fminf(fmaxf(acc[a][0], 0.f), 1.f), fminf(fmaxf(acc[a][1], 0.f), 1.f),
                         fminf(fmaxf(acc[a][2], 0.f), 1.f), fminf(fmaxf(acc[a][3], 0.f), 1.f)};
            float4 s1 = {fminf(fmaxf(acc[a][4], 0.f), 1.f), fminf(fmaxf(acc[a][5], 0.f), 1.f),
                         fminf(fmaxf(acc[a][6], 0.f), 1.f), fminf(fmaxf(acc[a][7], 0.f), 1.f)};
            *(float4*)&out[(size_t)i * NM + jb] = s0;
            *(float4*)&out[(size_t)i * NM + jb + 4] = s1;
        } else {
#pragma unroll
            for (int b = 0; b < 8; ++b) {
                int j = jb + b;
                if (j < NM) out[(size_t)i * NM + j] = fminf(fmaxf(acc[a][b], 0.f), 1.f);
            }
        }
    }
    if (bi != bj) {
#pragma unroll
        for (int b = 0; b < 8; ++b) {
            int j = bj * 128 + 8 * tx + b;
            if (j >= NM) break;
            int ib = bi * 128 + 8 * ty;
            if (ib + 7 < NM) {
                float4 s0 = {fminf(fmaxf(acc[0][b], 0.f), 1.f), fminf(fmaxf(acc[1][b], 0.f), 1.f),
                             fminf(fmaxf(acc[2][b], 0.f), 1.f), fminf(fmaxf(acc[3][b], 0.f), 1.f)};
                float4 s1 = {fminf(fmaxf(acc[4][b], 0.f), 1.f), fminf(fmaxf(acc[5][b], 0.f), 1.f),
                             fminf(fmaxf(acc[6][b], 0.f), 1.f), fminf(fmaxf(acc[7][b], 0.f), 1.f)};
                *(float4*)&out[(size_t)j * NM + ib] = s0;
                *(float4*)&out[(size_t)j * NM + ib + 4] = s1;
            } else {
#pragma unroll
                for (int a = 0; a < 8; ++a) {
                    int i = ib + a;
                    if (i < NM) out[(size_t)j * NM + i] = fminf(fmaxf(acc[a][b], 0.f), 1.f);
                }
            }
        }
    }
}

extern "C" void kernel_launch(void* const* d_in, const int* in_sizes, int n_in,
                              void* d_out, int out_size, void* d_ws, size_t ws_size,
                              hipStream_t stream) {
    const float* x     = (const float*)d_in[0];
    const float* W1    = (const float*)d_in[1];
    const float* gamma = (const float*)d_in[3];
    const float* beta  = (const float*)d_in[4];
    const float* W2    = (const float*)d_in[5];
    const float* b2    = (const float*)d_in[6];
    const float* V0    = (const float*)d_in[7];
    float* out = (float*)d_out;

    float* ws    = (float*)d_ws;
    float* S     = ws + OFF_S;
    float* sumw2 = ws + OFF_SUMW2;
    float* cvec  = ws + OFF_CVEC;
    float* W1s   = ws + OFF_W1S;
    float* wvec  = ws + OFF_WVEC;
    float* Wmat  = ws + OFF_WMAT;
    float* Va    = ws + OFF_VA;
    float* Vb    = ws + OFF_VB;

    zero_kernel<<<7, 256, 0, stream>>>(ws, OFF_W1S);   // S + sumw2
    stats_kernel<<<STATS_BLOCKS, 256, 0, stream>>>(x, S);
    bn_prep<<<HID, 64, 0, stream>>>(S, W1, gamma, beta, W1s, cvec);
    mlp_kernel<<<(PP + 255) / 256, 256, 0, stream>>>(x, W1s, cvec, W2, b2, wvec, sumw2);
    buildW<<<dim3(75, 75), 256, 0, stream>>>(wvec, Wmat);
    v0norm<<<NM / 4, 256, 0, stream>>>(V0, Va);
    for (int it = 0; it < SDP_ITERS; ++it) {
        const float* vin = (it & 1) ? Vb : Va;
        float* vout      = (it & 1) ? Va : Vb;
        sdp_step<<<SDP_BLOCKS, 960, 0, stream>>>(vin, vout, Wmat, sumw2);
    }
    // iter 99 (odd) writes Va
    vvt_kernel<<<dim3(10, 10), 256, 0, stream>>>(Va, out);
}